// Round 13
// baseline (563.544 us; speedup 1.0000x reference)
//
#include <hip/hip_runtime.h>
#include <hip/hip_bf16.h>
#include <float.h>

typedef _Float16 f16x8 __attribute__((ext_vector_type(8)));
typedef float f32x4 __attribute__((ext_vector_type(4)));

#define GRAPHS 64
#define NPG 2048
#define DIM 128
#define NNODES (GRAPHS * NPG)
#define NEDGES (NNODES * 16)
#define ECAP 32768   // edges per graph
#define NSB 8        // sub-blocks per graph for CSR build
#define RSLICES 16
#define RPB 256      // rows per block in sage_gemm

// ---------------- embed: xh[i] = (f16) emb[node_ids[i]] ----------------
__global__ __launch_bounds__(256) void embed_kernel(const int* __restrict__ ids,
    const float* __restrict__ emb, _Float16* __restrict__ xh) {
  int idx = blockIdx.x * 256 + threadIdx.x;
  int nd = idx >> 4, part = idx & 15;
  int id = ids[nd];
  const float* src = emb + (size_t)id * 128 + part * 8;
  float4 a = *(const float4*)(src);
  float4 b = *(const float4*)(src + 4);
  f16x8 o;
  o[0] = (_Float16)a.x; o[1] = (_Float16)a.y; o[2] = (_Float16)a.z; o[3] = (_Float16)a.w;
  o[4] = (_Float16)b.x; o[5] = (_Float16)b.y; o[6] = (_Float16)b.z; o[7] = (_Float16)b.w;
  *(f16x8*)(xh + (size_t)nd * 128 + part * 8) = o;
}

// ---------------- pre-convert weights to f16 in fragment order -----------
__global__ __launch_bounds__(256) void convert_w(const float* __restrict__ Wl,
    const float* __restrict__ Wr, _Float16* __restrict__ wh) {
  int qq = blockIdx.x * 256 + threadIdx.x;   // 0..4095
  int ks = qq >> 9, nf = (qq >> 6) & 7, l = qq & 63;
  int ncol = nf * 16 + (l & 15);
  int k0 = (ks & 3) * 32 + ((l >> 4) << 3);
  const float* wsrc = ((ks < 4) ? Wl : Wr) + ncol * 128 + k0;
  float4 a = *(const float4*)wsrc;
  float4 b = *(const float4*)(wsrc + 4);
  f16x8 w;
  w[0] = (_Float16)a.x; w[1] = (_Float16)a.y; w[2] = (_Float16)a.z; w[3] = (_Float16)a.w;
  w[4] = (_Float16)b.x; w[5] = (_Float16)b.y; w[6] = (_Float16)b.z; w[7] = (_Float16)b.w;
  *(f16x8*)(wh + (size_t)qq * 8) = w;
}

// ---------------- CSR build (layer 0 only), 3 phases ------------------------
__global__ __launch_bounds__(1024) void csr_hist(const int* __restrict__ src,
    const int* __restrict__ dst, int np, int* __restrict__ part) {
  __shared__ int hist[2048];
  int x = blockIdx.x;
  int s = x & 7, q = x >> 3;
  int b = q & (NSB - 1), gh = q >> 3;
  int g = gh * 8 + s;
  int tid = threadIdx.x;
  for (int i = tid; i < 2048; i += 1024) hist[i] = 0;
  __syncthreads();
  int e0 = g * ECAP + b * (ECAP / NSB);
  int nodebase = g * np;
  for (int e = tid; e < ECAP / NSB; e += 1024) {
    atomicAdd(&hist[dst[e0 + e] - nodebase], 1);
  }
  __syncthreads();
  for (int i = tid; i < np; i += 1024) part[((size_t)(g * NSB + b)) * 2048 + i] = hist[i];
}

__global__ __launch_bounds__(1024) void csr_scan(const int* __restrict__ part, int np,
    int* __restrict__ offb, int* __restrict__ deg, int* __restrict__ curs) {
  __shared__ int psum[1024];
  int g = blockIdx.x, tid = threadIdx.x;
  int i0 = 2 * tid, i1 = 2 * tid + 1;
  int p0[NSB], p1[NSB];
  int c0 = 0, c1 = 0;
#pragma unroll
  for (int b = 0; b < NSB; ++b) {
    p0[b] = (i0 < np) ? part[((size_t)(g * NSB + b)) * 2048 + i0] : 0;
    p1[b] = (i1 < np) ? part[((size_t)(g * NSB + b)) * 2048 + i1] : 0;
    c0 += p0[b]; c1 += p1[b];
  }
  int pair = c0 + c1;
  psum[tid] = pair;
  for (int s = 1; s < 1024; s <<= 1) {
    __syncthreads();
    int t = (tid >= s) ? psum[tid - s] : 0;
    __syncthreads();
    psum[tid] += t;
  }
  int excl = psum[tid] - pair;
  int ebase = g * ECAP;
  int nodebase = g * np;
  if (i0 < np) {
    int off = ebase + excl;
    offb[nodebase + i0] = off;
    deg[nodebase + i0] = c0;
    int cur = off;
#pragma unroll
    for (int b = 0; b < NSB; ++b) { curs[((size_t)(g * NSB + b)) * 2048 + i0] = cur; cur += p0[b]; }
  }
  if (i1 < np) {
    int off = ebase + excl + c0;
    offb[nodebase + i1] = off;
    deg[nodebase + i1] = c1;
    int cur = off;
#pragma unroll
    for (int b = 0; b < NSB; ++b) { curs[((size_t)(g * NSB + b)) * 2048 + i1] = cur; cur += p1[b]; }
  }
}

__global__ __launch_bounds__(1024) void csr_place(const int* __restrict__ src,
    const int* __restrict__ dst, int np, const int* __restrict__ curs,
    int* __restrict__ esort) {
  __shared__ int cur[2048];
  int x = blockIdx.x;
  int s = x & 7, q = x >> 3;
  int b = q & (NSB - 1), gh = q >> 3;
  int g = gh * 8 + s;
  int tid = threadIdx.x;
  for (int i = tid; i < np; i += 1024) cur[i] = curs[((size_t)(g * NSB + b)) * 2048 + i];
  __syncthreads();
  int e0 = g * ECAP + b * (ECAP / NSB);
  int nodebase = g * np;
  for (int e = tid; e < ECAP / NSB; e += 1024) {
    int ge = e0 + e;
    int p = atomicAdd(&cur[dst[ge] - nodebase], 1);
    esort[p] = src[ge];
  }
}

// ---------------- compose pool maps: A[v] = A[v]>=0 ? B[A[v]] : -1 ----------
__global__ __launch_bounds__(256) void compose_kernel(int* __restrict__ A,
    const int* __restrict__ B, int n) {
  int v = blockIdx.x * 256 + threadIdx.x;
  if (v >= n) return;
  int a = A[v];
  A[v] = (a >= 0) ? B[a] : -1;
}

// ---------------- remap edge list through pool map (streaming, 4/thread) -----
__global__ __launch_bounds__(256) void remap_esort(const int* __restrict__ esort0,
    const int* __restrict__ noo, int* __restrict__ esortl, int E4) {
  int t = blockIdx.x * 256 + threadIdx.x;
  if (t >= E4) return;
  int4 s = *(const int4*)(esort0 + t * 4);
  int4 o;
  o.x = noo[s.x]; o.y = noo[s.y]; o.z = noo[s.z]; o.w = noo[s.w];
  *(int4*)(esortl + t * 4) = o;
}

// ---------------- aggregate (layer 0): mean over incoming edges --------------
__global__ __launch_bounds__(256) void aggregate_kernel(const _Float16* __restrict__ xh,
    const int* __restrict__ offb, const int* __restrict__ deg, const int* __restrict__ esrc,
    _Float16* __restrict__ meanh, int np, int C) {
  int bid = blockIdx.x;
  int s = bid & 7, q = bid >> 3;
  int gsub = q / C, chunk = q - gsub * C;
  int g = gsub * 8 + s;
  int wave = threadIdx.x >> 6, lane = threadIdx.x & 63;
  int sub = lane >> 4, l = lane & 15;
  int local = chunk * 16 + wave * 4 + sub;
  if (local >= np) return;
  int w = g * np + local;
  int b = offb[w], c = deg[w];
  int e = b + c;
  float acc[8] = {0.f, 0.f, 0.f, 0.f, 0.f, 0.f, 0.f, 0.f};
  int i = b;
  for (; i + 4 <= e; i += 4) {
    int s0 = esrc[i], s1 = esrc[i + 1], s2 = esrc[i + 2], s3 = esrc[i + 3];
    f16x8 v0 = *(const f16x8*)(xh + (size_t)s0 * 128 + l * 8);
    f16x8 v1 = *(const f16x8*)(xh + (size_t)s1 * 128 + l * 8);
    f16x8 v2 = *(const f16x8*)(xh + (size_t)s2 * 128 + l * 8);
    f16x8 v3 = *(const f16x8*)(xh + (size_t)s3 * 128 + l * 8);
    f16x8 t = (v0 + v1) + (v2 + v3);
#pragma unroll
    for (int j = 0; j < 8; ++j) acc[j] += (float)t[j];
  }
  for (; i < e; ++i) {
    int srcn = esrc[i];
    f16x8 v = *(const f16x8*)(xh + (size_t)srcn * 128 + l * 8);
#pragma unroll
    for (int j = 0; j < 8; ++j) acc[j] += (float)v[j];
  }
  float inv = 1.f / (float)(c > 0 ? c : 1);
  f16x8 o;
#pragma unroll
  for (int j = 0; j < 8; ++j) o[j] = (_Float16)(acc[j] * inv);
  *(f16x8*)(meanh + (size_t)w * 128 + l * 8) = o;
}

// ---------------- aggregate (layers 1/2): pre-mapped edge list, -1 = dropped --
__global__ __launch_bounds__(256) void aggregate_f(const _Float16* __restrict__ xh,
    const int* __restrict__ offb0, const int* __restrict__ deg0, const int* __restrict__ esortl,
    const int* __restrict__ orig, _Float16* __restrict__ meanh, int np, int C) {
  int bid = blockIdx.x;
  int s = bid & 7, q = bid >> 3;
  int gsub = q / C, chunk = q - gsub * C;
  int g = gsub * 8 + s;
  int wave = threadIdx.x >> 6, lane = threadIdx.x & 63;
  int sub = lane >> 4, l = lane & 15;
  int local = chunk * 16 + wave * 4 + sub;
  if (local >= np) return;
  int w = g * np + local;
  int o = orig[w];
  int b = offb0[o], c0 = deg0[o];
  int e = b + c0;
  float acc[8] = {0.f, 0.f, 0.f, 0.f, 0.f, 0.f, 0.f, 0.f};
  int cnt = 0;
  const f16x8 zero = {(_Float16)0.f, (_Float16)0.f, (_Float16)0.f, (_Float16)0.f,
                      (_Float16)0.f, (_Float16)0.f, (_Float16)0.f, (_Float16)0.f};
  int i = b;
  for (; i + 4 <= e; i += 4) {
    int n0 = esortl[i], n1 = esortl[i + 1], n2 = esortl[i + 2], n3 = esortl[i + 3];
    f16x8 v0 = zero, v1 = zero, v2 = zero, v3 = zero;
    if (n0 >= 0) v0 = *(const f16x8*)(xh + (size_t)n0 * 128 + l * 8);
    if (n1 >= 0) v1 = *(const f16x8*)(xh + (size_t)n1 * 128 + l * 8);
    if (n2 >= 0) v2 = *(const f16x8*)(xh + (size_t)n2 * 128 + l * 8);
    if (n3 >= 0) v3 = *(const f16x8*)(xh + (size_t)n3 * 128 + l * 8);
    cnt += (n0 >= 0) + (n1 >= 0) + (n2 >= 0) + (n3 >= 0);
    f16x8 t = (v0 + v1) + (v2 + v3);
#pragma unroll
    for (int j = 0; j < 8; ++j) acc[j] += (float)t[j];
  }
  for (; i < e; ++i) {
    int sn = esortl[i];
    if (sn < 0) continue;
    ++cnt;
    f16x8 v = *(const f16x8*)(xh + (size_t)sn * 128 + l * 8);
#pragma unroll
    for (int j = 0; j < 8; ++j) acc[j] += (float)v[j];
  }
  float inv = 1.f / (float)(cnt > 0 ? cnt : 1);
  f16x8 ov;
#pragma unroll
  for (int j = 0; j < 8; ++j) ov[j] = (_Float16)(acc[j] * inv);
  *(f16x8*)(meanh + (size_t)w * 128 + l * 8) = ov;
}

// ---------------- fused SAGE transform + score (no LDS; weights via L2) -------
__global__ __launch_bounds__(256, 4) void sage_gemm(const _Float16* __restrict__ XH,
    const _Float16* MEANIN, _Float16* OUT, const _Float16* __restrict__ WH,
    const float* __restrict__ bl, const float* __restrict__ pw, float* __restrict__ sc,
    int n) {
  int tid = threadIdx.x;
  int wave = tid >> 6, lane = tid & 63;
  int wrow0 = blockIdx.x * RPB + wave * 64;
  if (wrow0 >= n) return;
  int kb = (lane >> 4) << 3;
  int lr = lane & 15;
  const f16x8* WHv = (const f16x8*)WH;
  f32x4 acc[4][8];
#pragma unroll
  for (int t = 0; t < 4; ++t)
#pragma unroll
    for (int nf = 0; nf < 8; ++nf) acc[t][nf] = (f32x4){0.f, 0.f, 0.f, 0.f};
#pragma unroll
  for (int ks = 0; ks < 8; ++ks) {
    const _Float16* A = (ks < 4) ? MEANIN : XH;
    const _Float16* ap = A + (size_t)(wrow0 + lr) * 128 + (ks & 3) * 32 + kb;
    f16x8 a0 = *(const f16x8*)(ap);
    f16x8 a1 = *(const f16x8*)(ap + 16 * 128);
    f16x8 a2 = *(const f16x8*)(ap + 32 * 128);
    f16x8 a3 = *(const f16x8*)(ap + 48 * 128);
#pragma unroll
    for (int nf = 0; nf < 8; ++nf) {
      f16x8 b = WHv[(ks * 8 + nf) * 64 + lane];
      acc[0][nf] = __builtin_amdgcn_mfma_f32_16x16x32_f16(a0, b, acc[0][nf], 0, 0, 0);
      acc[1][nf] = __builtin_amdgcn_mfma_f32_16x16x32_f16(a1, b, acc[1][nf], 0, 0, 0);
      acc[2][nf] = __builtin_amdgcn_mfma_f32_16x16x32_f16(a2, b, acc[2][nf], 0, 0, 0);
      acc[3][nf] = __builtin_amdgcn_mfma_f32_16x16x32_f16(a3, b, acc[3][nf], 0, 0, 0);
    }
  }
  float pwv[8], qn = 0.f;
#pragma unroll
  for (int nf = 0; nf < 8; ++nf) {
    pwv[nf] = pw[nf * 16 + lr];
    qn += pwv[nf] * pwv[nf];
  }
#pragma unroll
  for (int o = 1; o < 16; o <<= 1) qn += __shfl_xor(qn, o);
  float inv_n = 1.f / sqrtf(qn);
#pragma unroll
  for (int t = 0; t < 4; ++t) {
    int rbase = wrow0 + t * 16 + ((lane >> 4) << 2);
    float dot[4] = {0.f, 0.f, 0.f, 0.f};
#pragma unroll
    for (int nf = 0; nf < 8; ++nf) {
      int col = nf * 16 + lr;
      float bias = bl[col];
#pragma unroll
      for (int r = 0; r < 4; ++r) {
        float v = fmaxf(acc[t][nf][r] + bias, 0.f);
        OUT[(size_t)(rbase + r) * 128 + col] = (_Float16)v;
        dot[r] += v * pwv[nf];
      }
    }
#pragma unroll
    for (int r = 0; r < 4; ++r) {
#pragma unroll
      for (int o = 1; o < 16; o <<= 1) dot[r] += __shfl_xor(dot[r], o);
    }
    if (lr == 0) {
#pragma unroll
      for (int r = 0; r < 4; ++r) sc[rbase + r] = tanhf(dot[r] * inv_n);
    }
  }
}

// ---------------- per-graph top-k: hybrid LDS/register bitonic ----------------
__global__ __launch_bounds__(1024) void topk_kernel(const float* __restrict__ sc, int n_per, int k,
    float* __restrict__ ts, int* __restrict__ perm, int* __restrict__ noo) {
  __shared__ unsigned long long L[2048];
  int g = blockIdx.x;
  int tid = threadIdx.x;
  int lane = tid & 63, wave = tid >> 6;
  int i0 = wave * 128 + lane;
  int i1 = i0 + 64;
  const float* scg = sc + g * n_per;
  auto keyize = [&](int i) -> unsigned long long {
    float f = (i < n_per) ? scg[i] : -FLT_MAX;
    unsigned u = __float_as_uint(f);
    u = (u & 0x80000000u) ? ~u : (u | 0x80000000u);  // monotone float->uint map
    return ((unsigned long long)u << 32) | (unsigned)(2047 - i);
  };
  unsigned long long a = keyize(i0), b = keyize(i1);
#pragma clang loop unroll(disable)
  for (unsigned kk = 2; kk <= 2048; kk <<= 1) {
#pragma clang loop unroll(disable)
    for (unsigned j = kk >> 1; j >= 128; j >>= 1) {
      L[i0] = a; L[i1] = b;
      __syncthreads();
      unsigned long long pa = L[i0 ^ j], pb = L[i1 ^ j];
      bool dA = ((i0 & kk) == 0), lA = ((i0 & j) == 0);
      if ((dA == lA) ? (pa > a) : (pa < a)) a = pa;
      bool dB = ((i1 & kk) == 0), lB = ((i1 & j) == 0);
      if ((dB == lB) ? (pb > b) : (pb < b)) b = pb;
      __syncthreads();
    }
    if (kk >= 128) {
      bool desc = ((i0 & kk) == 0);
      if ((a < b) == desc) { unsigned long long t = a; a = b; b = t; }
    }
    unsigned jtop = (kk >> 1 < 32u) ? (kk >> 1) : 32u;
#pragma clang loop unroll(disable)
    for (unsigned j = jtop; j >= 1; j >>= 1) {
      unsigned long long oa = __shfl_xor(a, (int)j);
      unsigned long long ob = __shfl_xor(b, (int)j);
      bool low = ((lane & j) == 0);
      bool dA = ((i0 & kk) == 0);
      if ((dA == low) ? (oa > a) : (oa < a)) a = oa;
      bool dB = ((i1 & kk) == 0);
      if ((dB == low) ? (ob > b) : (ob < b)) b = ob;
    }
  }
  auto emit = [&](unsigned long long v, int rank) {
    int orig = 2047 - (int)(v & 0xFFFFFFFFu);
    if (orig < n_per) {
      if (rank < k) {
        int ng = g * k + rank;
        ts[ng] = scg[orig];
        perm[ng] = g * n_per + orig;
        noo[g * n_per + orig] = ng;
      } else {
        noo[g * n_per + orig] = -1;
      }
    }
  };
  emit(a, i0);
  emit(b, i1);
}

// ---------------- gather + scale + ORIG compose ------------------------------
__global__ __launch_bounds__(256) void gather_kernel(const _Float16* __restrict__ xold,
    const int* __restrict__ perm, const float* __restrict__ ts, _Float16* __restrict__ xh,
    const int* __restrict__ orig_in, int* __restrict__ orig_out, int n_new) {
  int idx = blockIdx.x * 256 + threadIdx.x;
  int v = idx >> 4, part = idx & 15;
  if (v >= n_new) return;
  int p = perm[v];
  if (part == 0) orig_out[v] = orig_in ? orig_in[p] : p;
  float t = ts[v];
  f16x8 a = *(const f16x8*)(xold + (size_t)p * 128 + part * 8);
  f16x8 o;
#pragma unroll
  for (int j = 0; j < 8; ++j) o[j] = (_Float16)((float)a[j] * t);
  *(f16x8*)(xh + (size_t)v * 128 + part * 8) = o;
}

// ---------------- readout stage 1: per-(graph,slice) partial max/sum ----------------
__global__ __launch_bounds__(256) void readout_part(const _Float16* __restrict__ x, int k,
    float* __restrict__ pmax, float* __restrict__ psum) {
  int g = blockIdx.x >> 4;           // / RSLICES
  int slice = blockIdx.x & (RSLICES - 1);
  int d = threadIdx.x & 127;
  int half = threadIdx.x >> 7;       // 0 or 1
  int rpb = (k + RSLICES - 1) / RSLICES;
  int r0 = slice * rpb;
  int r1 = r0 + rpb; if (r1 > k) r1 = k;
  float vmax = -FLT_MAX, vs = 0.f;
  for (int r = r0 + half; r < r1; r += 2) {
    float v = (float)x[((size_t)g * k + r) * 128 + d];
    vmax = fmaxf(vmax, v);
    vs += v;
  }
  __shared__ float smax[256], ssum[256];
  smax[threadIdx.x] = vmax;
  ssum[threadIdx.x] = vs;
  __syncthreads();
  if (threadIdx.x < 128) {
    vmax = fmaxf(smax[threadIdx.x], smax[threadIdx.x + 128]);
    vs = ssum[threadIdx.x] + ssum[threadIdx.x + 128];
    pmax[(size_t)(g * RSLICES + slice) * 128 + d] = vmax;
    psum[(size_t)(g * RSLICES + slice) * 128 + d] = vs;
  }
}

// ---------------- readout stage 2: combine slices, h[g] += [max, mean] ----------------
__global__ __launch_bounds__(256) void readout_comb(const float* __restrict__ pmax,
    const float* __restrict__ psum, int k, float* __restrict__ h) {
  int idx = blockIdx.x * 256 + threadIdx.x;  // 64*128
  int g = idx >> 7, d = idx & 127;
  float vmax = -FLT_MAX, vs = 0.f;
#pragma unroll
  for (int s = 0; s < RSLICES; ++s) {
    vmax = fmaxf(vmax, pmax[(size_t)(g * RSLICES + s) * 128 + d]);
    vs += psum[(size_t)(g * RSLICES + s) * 128 + d];
  }
  h[g * 256 + d] += vmax;
  h[g * 256 + 128 + d] += vs / (float)k;
}

// ---------------- final MLP ----------------
__global__ __launch_bounds__(256) void mlp1(const float* __restrict__ h, const float* __restrict__ W1,
    const float* __restrict__ b1, float* __restrict__ h1) {
  int o = blockIdx.x * 256 + threadIdx.x;  // 64*128
  int g = o >> 7, j = o & 127;
  const float* hp = h + g * 256;
  const float* wp = W1 + j * 256;
  float a = b1[j];
  for (int c = 0; c < 256; ++c) a += hp[c] * wp[c];
  h1[o] = fmaxf(a, 0.f);
}

__global__ __launch_bounds__(256) void mlp2(const float* __restrict__ h1, const float* __restrict__ W2,
    const float* __restrict__ b2, float* __restrict__ h2) {
  int o = blockIdx.x * 256 + threadIdx.x;  // 64*64
  int g = o >> 6, j = o & 63;
  const float* hp = h1 + g * 128;
  const float* wp = W2 + j * 128;
  float a = b2[j];
  for (int c = 0; c < 128; ++c) a += hp[c] * wp[c];
  h2[o] = fmaxf(a, 0.f);
}

__global__ __launch_bounds__(64) void mlp3(const float* __restrict__ h2, const float* __restrict__ W3,
    const float* __restrict__ b3, float* __restrict__ out) {
  int g = threadIdx.x;
  if (g >= 64) return;
  const float* hp = h2 + g * 64;
  float a = b3[0];
  for (int c = 0; c < 64; ++c) a += hp[c] * W3[c];
  out[g] = 1.f / (1.f + expf(-a));
}

extern "C" void kernel_launch(void* const* d_in, const int* in_sizes, int n_in,
                              void* d_out, int out_size, void* d_ws, size_t ws_size,
                              hipStream_t stream) {
  const int* node_ids = (const int*)d_in[0];
  const int* ei = (const int*)d_in[1];
  const float* emb = (const float*)d_in[3];
  const float* W[3][4] = {
      {(const float*)d_in[4], (const float*)d_in[5], (const float*)d_in[6], (const float*)d_in[7]},
      {(const float*)d_in[8], (const float*)d_in[9], (const float*)d_in[10], (const float*)d_in[11]},
      {(const float*)d_in[12], (const float*)d_in[13], (const float*)d_in[14], (const float*)d_in[15]}};
  const float* W1 = (const float*)d_in[16];
  const float* b1 = (const float*)d_in[17];
  const float* W2 = (const float*)d_in[18];
  const float* b2 = (const float*)d_in[19];
  const float* W3 = (const float*)d_in[20];
  const float* b3 = (const float*)d_in[21];
  float* out = (float*)d_out;

  const int E = NEDGES;
  char* ws = (char*)d_ws;
  size_t o = 0;
  auto alloc = [&](size_t bytes) { void* p = ws + o; o = (o + bytes + 255) & ~(size_t)255; return p; };
  _Float16* XH = (_Float16*)alloc((size_t)NNODES * 128 * 2);
  _Float16* MEANH = (_Float16*)alloc((size_t)NNODES * 128 * 2);
  int* ESORT = (int*)alloc((size_t)E * 4);
  int* ESORTL = (int*)alloc((size_t)E * 4);
  int* PART = (int*)alloc((size_t)GRAPHS * NSB * 2048 * 4);
  int* CURS = (int*)alloc((size_t)GRAPHS * NSB * 2048 * 4);
  int* OFFB = (int*)alloc((size_t)NNODES * 4);
  int* DEG = (int*)alloc((size_t)NNODES * 4);
  float* SC = (float*)alloc((size_t)NNODES * 4);
  float* TS = (float*)alloc((size_t)NNODES * 4);
  int* PERM = (int*)alloc((size_t)NNODES * 4);
  int* NOOA = (int*)alloc((size_t)NNODES * 4);
  int* NOOB = (int*)alloc((size_t)NNODES * 4);
  int* ORIGA = (int*)alloc((size_t)NNODES * 4);
  int* ORIGB = (int*)alloc((size_t)NNODES * 4);
  _Float16* WH0 = (_Float16*)alloc(4096 * 8 * 2);
  _Float16* WH1 = (_Float16*)alloc(4096 * 8 * 2);
  _Float16* WH2 = (_Float16*)alloc(4096 * 8 * 2);
  float* PMAX = (float*)alloc((size_t)GRAPHS * RSLICES * 128 * 4);
  float* PSUM = (float*)alloc((size_t)GRAPHS * RSLICES * 128 * 4);
  float* H = (float*)alloc(64 * 256 * 4);
  float* H1 = (float*)alloc(64 * 128 * 4);
  float* H2 = (float*)alloc(64 * 64 * 4);

  embed_kernel<<<NNODES * 16 / 256, 256, 0, stream>>>(node_ids, emb, XH);
  hipMemsetAsync(H, 0, 64 * 256 * 4, stream);
  convert_w<<<16, 256, 0, stream>>>(W[0][0], W[0][1], WH0);
  convert_w<<<16, 256, 0, stream>>>(W[1][0], W[1][1], WH1);
  convert_w<<<16, 256, 0, stream>>>(W[2][0], W[2][1], WH2);

  // layer-0 CSR (built once; layers 1/2 use remapped edge values)
  const int* src = ei;
  const int* dst = ei + E;
  csr_hist<<<GRAPHS * NSB, 1024, 0, stream>>>(src, dst, NPG, PART);
  csr_scan<<<GRAPHS, 1024, 0, stream>>>(PART, NPG, OFFB, DEG, CURS);
  csr_place<<<GRAPHS * NSB, 1024, 0, stream>>>(src, dst, NPG, CURS, ESORT);

  struct LayerP { int n, k; };                 // n = current node count; k = keep per graph
  LayerP L[3] = {{131072, 1639}, {104896, 1312}, {83968, 1050}};
  _Float16* WHs[3] = {WH0, WH1, WH2};
  int* ORIG_cur = ORIGA;   // maps current ids -> original ids (valid for li>=1)
  int* ORIG_next = ORIGB;

  for (int li = 0; li < 3; ++li) {
    int n = L[li].n, k = L[li].k;
    int np = n / 64;
    int n_new = 64 * k;
    const float *bl = W[li][2], *pw = W[li][3];

    int C = (np + 15) / 16;
    if (li == 0) {
      aggregate_kernel<<<64 * C, 256, 0, stream>>>(XH, OFFB, DEG, ESORT, MEANH, np, C);
    } else {
      remap_esort<<<E / 4 / 256, 256, 0, stream>>>(ESORT, NOOA, ESORTL, E / 4);
      aggregate_f<<<64 * C, 256, 0, stream>>>(XH, OFFB, DEG, ESORTL, ORIG_cur,
                                              MEANH, np, C);
    }
    sage_gemm<<<(n + RPB - 1) / RPB, 256, 0, stream>>>(XH, MEANH, MEANH, WHs[li], bl, pw, SC, n);
    topk_kernel<<<GRAPHS, 1024, 0, stream>>>(SC, np, k, TS, PERM, (li == 0) ? NOOA : NOOB);
    gather_kernel<<<n_new * 16 / 256, 256, 0, stream>>>(MEANH, PERM, TS, XH,
        (li == 0) ? nullptr : ORIG_cur, ORIG_next, n_new);
    { int* t = ORIG_cur; ORIG_cur = ORIG_next; ORIG_next = t; }
    readout_part<<<GRAPHS * RSLICES, 256, 0, stream>>>(XH, k, PMAX, PSUM);
    readout_comb<<<32, 256, 0, stream>>>(PMAX, PSUM, k, H);
    if (li == 1) compose_kernel<<<NNODES / 256, 256, 0, stream>>>(NOOA, NOOB, NNODES);
  }

  mlp1<<<32, 256, 0, stream>>>(H, W1, b1, H1);
  mlp2<<<16, 256, 0, stream>>>(H1, W2, b2, H2);
  mlp3<<<1, 64, 0, stream>>>(H2, W3, b3, out);
}

// Round 14
// 393.263 us; speedup vs baseline: 1.4330x; 1.4330x over previous
//
#include <hip/hip_runtime.h>
#include <hip/hip_bf16.h>
#include <float.h>

typedef _Float16 f16x8 __attribute__((ext_vector_type(8)));
typedef float f32x4 __attribute__((ext_vector_type(4)));

#define GRAPHS 64
#define NPG 2048
#define DIM 128
#define NNODES (GRAPHS * NPG)
#define NEDGES (NNODES * 16)
#define ECAP 32768   // edges per graph
#define NSB 8        // sub-blocks per graph for CSR build
#define RSLICES 16
#define RPB 256      // rows per block in sage_gemm

// ---------------- embed: xh[i] = (f16) emb[node_ids[i]] ----------------
__global__ __launch_bounds__(256) void embed_kernel(const int* __restrict__ ids,
    const float* __restrict__ emb, _Float16* __restrict__ xh) {
  int idx = blockIdx.x * 256 + threadIdx.x;
  int nd = idx >> 4, part = idx & 15;
  int id = ids[nd];
  const float* src = emb + (size_t)id * 128 + part * 8;
  float4 a = *(const float4*)(src);
  float4 b = *(const float4*)(src + 4);
  f16x8 o;
  o[0] = (_Float16)a.x; o[1] = (_Float16)a.y; o[2] = (_Float16)a.z; o[3] = (_Float16)a.w;
  o[4] = (_Float16)b.x; o[5] = (_Float16)b.y; o[6] = (_Float16)b.z; o[7] = (_Float16)b.w;
  *(f16x8*)(xh + (size_t)nd * 128 + part * 8) = o;
}

// ---------------- pre-convert weights to f16 in LDS-staging order -----------
__global__ __launch_bounds__(256) void convert_w(const float* __restrict__ Wl,
    const float* __restrict__ Wr, _Float16* __restrict__ wh) {
  int qq = blockIdx.x * 256 + threadIdx.x;   // 0..4095
  int ks = qq >> 9, nf = (qq >> 6) & 7, l = qq & 63;
  int ncol = nf * 16 + (l & 15);
  int k0 = (ks & 3) * 32 + ((l >> 4) << 3);
  const float* wsrc = ((ks < 4) ? Wl : Wr) + ncol * 128 + k0;
  float4 a = *(const float4*)wsrc;
  float4 b = *(const float4*)(wsrc + 4);
  f16x8 w;
  w[0] = (_Float16)a.x; w[1] = (_Float16)a.y; w[2] = (_Float16)a.z; w[3] = (_Float16)a.w;
  w[4] = (_Float16)b.x; w[5] = (_Float16)b.y; w[6] = (_Float16)b.z; w[7] = (_Float16)b.w;
  *(f16x8*)(wh + (size_t)qq * 8) = w;
}

// ---------------- CSR build (layer 0 only), 3 phases ------------------------
__global__ __launch_bounds__(1024) void csr_hist(const int* __restrict__ src,
    const int* __restrict__ dst, int np, int* __restrict__ part) {
  __shared__ int hist[2048];
  int x = blockIdx.x;
  int s = x & 7, q = x >> 3;
  int b = q & (NSB - 1), gh = q >> 3;
  int g = gh * 8 + s;
  int tid = threadIdx.x;
  for (int i = tid; i < 2048; i += 1024) hist[i] = 0;
  __syncthreads();
  int e0 = g * ECAP + b * (ECAP / NSB);
  int nodebase = g * np;
  for (int e = tid; e < ECAP / NSB; e += 1024) {
    atomicAdd(&hist[dst[e0 + e] - nodebase], 1);
  }
  __syncthreads();
  for (int i = tid; i < np; i += 1024) part[((size_t)(g * NSB + b)) * 2048 + i] = hist[i];
}

__global__ __launch_bounds__(1024) void csr_scan(const int* __restrict__ part, int np,
    int* __restrict__ offb, int* __restrict__ deg, int* __restrict__ curs) {
  __shared__ int psum[1024];
  int g = blockIdx.x, tid = threadIdx.x;
  int i0 = 2 * tid, i1 = 2 * tid + 1;
  int p0[NSB], p1[NSB];
  int c0 = 0, c1 = 0;
#pragma unroll
  for (int b = 0; b < NSB; ++b) {
    p0[b] = (i0 < np) ? part[((size_t)(g * NSB + b)) * 2048 + i0] : 0;
    p1[b] = (i1 < np) ? part[((size_t)(g * NSB + b)) * 2048 + i1] : 0;
    c0 += p0[b]; c1 += p1[b];
  }
  int pair = c0 + c1;
  psum[tid] = pair;
  for (int s = 1; s < 1024; s <<= 1) {
    __syncthreads();
    int t = (tid >= s) ? psum[tid - s] : 0;
    __syncthreads();
    psum[tid] += t;
  }
  int excl = psum[tid] - pair;
  int ebase = g * ECAP;
  int nodebase = g * np;
  if (i0 < np) {
    int off = ebase + excl;
    offb[nodebase + i0] = off;
    deg[nodebase + i0] = c0;
    int cur = off;
#pragma unroll
    for (int b = 0; b < NSB; ++b) { curs[((size_t)(g * NSB + b)) * 2048 + i0] = cur; cur += p0[b]; }
  }
  if (i1 < np) {
    int off = ebase + excl + c0;
    offb[nodebase + i1] = off;
    deg[nodebase + i1] = c1;
    int cur = off;
#pragma unroll
    for (int b = 0; b < NSB; ++b) { curs[((size_t)(g * NSB + b)) * 2048 + i1] = cur; cur += p1[b]; }
  }
}

__global__ __launch_bounds__(1024) void csr_place(const int* __restrict__ src,
    const int* __restrict__ dst, int np, const int* __restrict__ curs,
    int* __restrict__ esort) {
  __shared__ int cur[2048];
  int x = blockIdx.x;
  int s = x & 7, q = x >> 3;
  int b = q & (NSB - 1), gh = q >> 3;
  int g = gh * 8 + s;
  int tid = threadIdx.x;
  for (int i = tid; i < np; i += 1024) cur[i] = curs[((size_t)(g * NSB + b)) * 2048 + i];
  __syncthreads();
  int e0 = g * ECAP + b * (ECAP / NSB);
  int nodebase = g * np;
  for (int e = tid; e < ECAP / NSB; e += 1024) {
    int ge = e0 + e;
    int p = atomicAdd(&cur[dst[ge] - nodebase], 1);
    esort[p] = src[ge];
  }
}

// ---------------- compose pool maps: A[v] = A[v]>=0 ? B[A[v]] : -1 ----------
__global__ __launch_bounds__(256) void compose_kernel(int* __restrict__ A,
    const int* __restrict__ B, int n) {
  int v = blockIdx.x * 256 + threadIdx.x;
  if (v >= n) return;
  int a = A[v];
  A[v] = (a >= 0) ? B[a] : -1;
}

// ---------------- remap edge list through pool map (streaming, 4/thread) -----
__global__ __launch_bounds__(256) void remap_esort(const int* __restrict__ esort0,
    const int* __restrict__ noo, int* __restrict__ esortl, int E4) {
  int t = blockIdx.x * 256 + threadIdx.x;
  if (t >= E4) return;
  int4 s = *(const int4*)(esort0 + t * 4);
  int4 o;
  o.x = noo[s.x]; o.y = noo[s.y]; o.z = noo[s.z]; o.w = noo[s.w];
  *(int4*)(esortl + t * 4) = o;
}

// ---------------- aggregate (layer 0): mean over incoming edges --------------
__global__ __launch_bounds__(256) void aggregate_kernel(const _Float16* __restrict__ xh,
    const int* __restrict__ offb, const int* __restrict__ deg, const int* __restrict__ esrc,
    _Float16* __restrict__ meanh, int np, int C) {
  int bid = blockIdx.x;
  int s = bid & 7, q = bid >> 3;
  int gsub = q / C, chunk = q - gsub * C;
  int g = gsub * 8 + s;
  int wave = threadIdx.x >> 6, lane = threadIdx.x & 63;
  int sub = lane >> 4, l = lane & 15;
  int local = chunk * 16 + wave * 4 + sub;
  if (local >= np) return;
  int w = g * np + local;
  int b = offb[w], c = deg[w];
  int e = b + c;
  float acc[8] = {0.f, 0.f, 0.f, 0.f, 0.f, 0.f, 0.f, 0.f};
  int i = b;
  for (; i + 4 <= e; i += 4) {
    int s0 = esrc[i], s1 = esrc[i + 1], s2 = esrc[i + 2], s3 = esrc[i + 3];
    f16x8 v0 = *(const f16x8*)(xh + (size_t)s0 * 128 + l * 8);
    f16x8 v1 = *(const f16x8*)(xh + (size_t)s1 * 128 + l * 8);
    f16x8 v2 = *(const f16x8*)(xh + (size_t)s2 * 128 + l * 8);
    f16x8 v3 = *(const f16x8*)(xh + (size_t)s3 * 128 + l * 8);
    f16x8 t = (v0 + v1) + (v2 + v3);
#pragma unroll
    for (int j = 0; j < 8; ++j) acc[j] += (float)t[j];
  }
  for (; i < e; ++i) {
    int srcn = esrc[i];
    f16x8 v = *(const f16x8*)(xh + (size_t)srcn * 128 + l * 8);
#pragma unroll
    for (int j = 0; j < 8; ++j) acc[j] += (float)v[j];
  }
  float inv = 1.f / (float)(c > 0 ? c : 1);
  f16x8 o;
#pragma unroll
  for (int j = 0; j < 8; ++j) o[j] = (_Float16)(acc[j] * inv);
  *(f16x8*)(meanh + (size_t)w * 128 + l * 8) = o;
}

// ---------------- aggregate (layers 1/2): pre-mapped edge list, -1 = dropped --
__global__ __launch_bounds__(256) void aggregate_f(const _Float16* __restrict__ xh,
    const int* __restrict__ offb0, const int* __restrict__ deg0, const int* __restrict__ esortl,
    const int* __restrict__ orig, _Float16* __restrict__ meanh, int np, int C) {
  int bid = blockIdx.x;
  int s = bid & 7, q = bid >> 3;
  int gsub = q / C, chunk = q - gsub * C;
  int g = gsub * 8 + s;
  int wave = threadIdx.x >> 6, lane = threadIdx.x & 63;
  int sub = lane >> 4, l = lane & 15;
  int local = chunk * 16 + wave * 4 + sub;
  if (local >= np) return;
  int w = g * np + local;
  int o = orig[w];
  int b = offb0[o], c0 = deg0[o];
  int e = b + c0;
  float acc[8] = {0.f, 0.f, 0.f, 0.f, 0.f, 0.f, 0.f, 0.f};
  int cnt = 0;
  const f16x8 zero = {(_Float16)0.f, (_Float16)0.f, (_Float16)0.f, (_Float16)0.f,
                      (_Float16)0.f, (_Float16)0.f, (_Float16)0.f, (_Float16)0.f};
  int i = b;
  for (; i + 4 <= e; i += 4) {
    int n0 = esortl[i], n1 = esortl[i + 1], n2 = esortl[i + 2], n3 = esortl[i + 3];
    f16x8 v0 = zero, v1 = zero, v2 = zero, v3 = zero;
    if (n0 >= 0) v0 = *(const f16x8*)(xh + (size_t)n0 * 128 + l * 8);
    if (n1 >= 0) v1 = *(const f16x8*)(xh + (size_t)n1 * 128 + l * 8);
    if (n2 >= 0) v2 = *(const f16x8*)(xh + (size_t)n2 * 128 + l * 8);
    if (n3 >= 0) v3 = *(const f16x8*)(xh + (size_t)n3 * 128 + l * 8);
    cnt += (n0 >= 0) + (n1 >= 0) + (n2 >= 0) + (n3 >= 0);
    f16x8 t = (v0 + v1) + (v2 + v3);
#pragma unroll
    for (int j = 0; j < 8; ++j) acc[j] += (float)t[j];
  }
  for (; i < e; ++i) {
    int sn = esortl[i];
    if (sn < 0) continue;
    ++cnt;
    f16x8 v = *(const f16x8*)(xh + (size_t)sn * 128 + l * 8);
#pragma unroll
    for (int j = 0; j < 8; ++j) acc[j] += (float)v[j];
  }
  float inv = 1.f / (float)(cnt > 0 ? cnt : 1);
  f16x8 ov;
#pragma unroll
  for (int j = 0; j < 8; ++j) ov[j] = (_Float16)(acc[j] * inv);
  *(f16x8*)(meanh + (size_t)w * 128 + l * 8) = ov;
}

// ---------------- fused SAGE transform + score (LDS weight stage) -------------
__global__ __launch_bounds__(256, 2) void sage_gemm(const _Float16* __restrict__ XH,
    const _Float16* MEANIN, _Float16* OUT, const _Float16* __restrict__ WH,
    const float* __restrict__ bl, const float* __restrict__ pw, float* __restrict__ sc,
    int n) {
  __shared__ _Float16 WB[4096 * 8];  // 64KB, layout [ks][nf][lane][8]
  int tid = threadIdx.x;
  for (int qq = tid; qq < 4096; qq += 256)
    *(f16x8*)(WB + qq * 8) = *(const f16x8*)(WH + (size_t)qq * 8);
  __syncthreads();
  int wave = tid >> 6, lane = tid & 63;
  int wrow0 = blockIdx.x * RPB + wave * 64;
  if (wrow0 >= n) return;
  int kb = (lane >> 4) << 3;
  int lr = lane & 15;
  f32x4 acc[4][8];
#pragma unroll
  for (int t = 0; t < 4; ++t)
#pragma unroll
    for (int nf = 0; nf < 8; ++nf) acc[t][nf] = (f32x4){0.f, 0.f, 0.f, 0.f};
#pragma unroll
  for (int ks = 0; ks < 8; ++ks) {
    const _Float16* A = (ks < 4) ? MEANIN : XH;
    const _Float16* ap = A + (size_t)(wrow0 + lr) * 128 + (ks & 3) * 32 + kb;
    f16x8 a0 = *(const f16x8*)(ap);
    f16x8 a1 = *(const f16x8*)(ap + 16 * 128);
    f16x8 a2 = *(const f16x8*)(ap + 32 * 128);
    f16x8 a3 = *(const f16x8*)(ap + 48 * 128);
#pragma unroll
    for (int nf = 0; nf < 8; ++nf) {
      f16x8 b = *(const f16x8*)(WB + ((ks * 8 + nf) * 64 + lane) * 8);
      acc[0][nf] = __builtin_amdgcn_mfma_f32_16x16x32_f16(a0, b, acc[0][nf], 0, 0, 0);
      acc[1][nf] = __builtin_amdgcn_mfma_f32_16x16x32_f16(a1, b, acc[1][nf], 0, 0, 0);
      acc[2][nf] = __builtin_amdgcn_mfma_f32_16x16x32_f16(a2, b, acc[2][nf], 0, 0, 0);
      acc[3][nf] = __builtin_amdgcn_mfma_f32_16x16x32_f16(a3, b, acc[3][nf], 0, 0, 0);
    }
  }
  float pwv[8], qn = 0.f;
#pragma unroll
  for (int nf = 0; nf < 8; ++nf) {
    pwv[nf] = pw[nf * 16 + lr];
    qn += pwv[nf] * pwv[nf];
  }
#pragma unroll
  for (int o = 1; o < 16; o <<= 1) qn += __shfl_xor(qn, o);
  float inv_n = 1.f / sqrtf(qn);
#pragma unroll
  for (int t = 0; t < 4; ++t) {
    int rbase = wrow0 + t * 16 + ((lane >> 4) << 2);
    float dot[4] = {0.f, 0.f, 0.f, 0.f};
#pragma unroll
    for (int nf = 0; nf < 8; ++nf) {
      int col = nf * 16 + lr;
      float bias = bl[col];
#pragma unroll
      for (int r = 0; r < 4; ++r) {
        float v = fmaxf(acc[t][nf][r] + bias, 0.f);
        OUT[(size_t)(rbase + r) * 128 + col] = (_Float16)v;
        dot[r] += v * pwv[nf];
      }
    }
#pragma unroll
    for (int r = 0; r < 4; ++r) {
#pragma unroll
      for (int o = 1; o < 16; o <<= 1) dot[r] += __shfl_xor(dot[r], o);
    }
    if (lr == 0) {
#pragma unroll
      for (int r = 0; r < 4; ++r) sc[rbase + r] = tanhf(dot[r] * inv_n);
    }
  }
}

// ---------------- per-graph top-k: hybrid LDS/register bitonic ----------------
__global__ __launch_bounds__(1024) void topk_kernel(const float* __restrict__ sc, int n_per, int k,
    float* __restrict__ ts, int* __restrict__ perm, int* __restrict__ noo) {
  __shared__ unsigned long long L[2048];
  int g = blockIdx.x;
  int tid = threadIdx.x;
  int lane = tid & 63, wave = tid >> 6;
  int i0 = wave * 128 + lane;
  int i1 = i0 + 64;
  const float* scg = sc + g * n_per;
  auto keyize = [&](int i) -> unsigned long long {
    float f = (i < n_per) ? scg[i] : -FLT_MAX;
    unsigned u = __float_as_uint(f);
    u = (u & 0x80000000u) ? ~u : (u | 0x80000000u);  // monotone float->uint map
    return ((unsigned long long)u << 32) | (unsigned)(2047 - i);
  };
  unsigned long long a = keyize(i0), b = keyize(i1);
#pragma clang loop unroll(disable)
  for (unsigned kk = 2; kk <= 2048; kk <<= 1) {
#pragma clang loop unroll(disable)
    for (unsigned j = kk >> 1; j >= 128; j >>= 1) {
      L[i0] = a; L[i1] = b;
      __syncthreads();
      unsigned long long pa = L[i0 ^ j], pb = L[i1 ^ j];
      bool dA = ((i0 & kk) == 0), lA = ((i0 & j) == 0);
      if ((dA == lA) ? (pa > a) : (pa < a)) a = pa;
      bool dB = ((i1 & kk) == 0), lB = ((i1 & j) == 0);
      if ((dB == lB) ? (pb > b) : (pb < b)) b = pb;
      __syncthreads();
    }
    if (kk >= 128) {
      bool desc = ((i0 & kk) == 0);
      if ((a < b) == desc) { unsigned long long t = a; a = b; b = t; }
    }
    unsigned jtop = (kk >> 1 < 32u) ? (kk >> 1) : 32u;
#pragma clang loop unroll(disable)
    for (unsigned j = jtop; j >= 1; j >>= 1) {
      unsigned long long oa = __shfl_xor(a, (int)j);
      unsigned long long ob = __shfl_xor(b, (int)j);
      bool low = ((lane & j) == 0);
      bool dA = ((i0 & kk) == 0);
      if ((dA == low) ? (oa > a) : (oa < a)) a = oa;
      bool dB = ((i1 & kk) == 0);
      if ((dB == low) ? (ob > b) : (ob < b)) b = ob;
    }
  }
  auto emit = [&](unsigned long long v, int rank) {
    int orig = 2047 - (int)(v & 0xFFFFFFFFu);
    if (orig < n_per) {
      if (rank < k) {
        int ng = g * k + rank;
        ts[ng] = scg[orig];
        perm[ng] = g * n_per + orig;
        noo[g * n_per + orig] = ng;
      } else {
        noo[g * n_per + orig] = -1;
      }
    }
  };
  emit(a, i0);
  emit(b, i1);
}

// ---------------- gather + scale + ORIG compose ------------------------------
__global__ __launch_bounds__(256) void gather_kernel(const _Float16* __restrict__ xold,
    const int* __restrict__ perm, const float* __restrict__ ts, _Float16* __restrict__ xh,
    const int* __restrict__ orig_in, int* __restrict__ orig_out, int n_new) {
  int idx = blockIdx.x * 256 + threadIdx.x;
  int v = idx >> 4, part = idx & 15;
  if (v >= n_new) return;
  int p = perm[v];
  if (part == 0) orig_out[v] = orig_in ? orig_in[p] : p;
  float t = ts[v];
  f16x8 a = *(const f16x8*)(xold + (size_t)p * 128 + part * 8);
  f16x8 o;
#pragma unroll
  for (int j = 0; j < 8; ++j) o[j] = (_Float16)((float)a[j] * t);
  *(f16x8*)(xh + (size_t)v * 128 + part * 8) = o;
}

// ---------------- readout stage 1: per-(graph,slice) partial max/sum ----------------
__global__ __launch_bounds__(256) void readout_part(const _Float16* __restrict__ x, int k,
    float* __restrict__ pmax, float* __restrict__ psum) {
  int g = blockIdx.x >> 4;           // / RSLICES
  int slice = blockIdx.x & (RSLICES - 1);
  int d = threadIdx.x & 127;
  int half = threadIdx.x >> 7;       // 0 or 1
  int rpb = (k + RSLICES - 1) / RSLICES;
  int r0 = slice * rpb;
  int r1 = r0 + rpb; if (r1 > k) r1 = k;
  float vmax = -FLT_MAX, vs = 0.f;
  for (int r = r0 + half; r < r1; r += 2) {
    float v = (float)x[((size_t)g * k + r) * 128 + d];
    vmax = fmaxf(vmax, v);
    vs += v;
  }
  __shared__ float smax[256], ssum[256];
  smax[threadIdx.x] = vmax;
  ssum[threadIdx.x] = vs;
  __syncthreads();
  if (threadIdx.x < 128) {
    vmax = fmaxf(smax[threadIdx.x], smax[threadIdx.x + 128]);
    vs = ssum[threadIdx.x] + ssum[threadIdx.x + 128];
    pmax[(size_t)(g * RSLICES + slice) * 128 + d] = vmax;
    psum[(size_t)(g * RSLICES + slice) * 128 + d] = vs;
  }
}

// ---------------- readout stage 2: combine slices, h[g] += [max, mean] ----------------
__global__ __launch_bounds__(256) void readout_comb(const float* __restrict__ pmax,
    const float* __restrict__ psum, int k, float* __restrict__ h) {
  int idx = blockIdx.x * 256 + threadIdx.x;  // 64*128
  int g = idx >> 7, d = idx & 127;
  float vmax = -FLT_MAX, vs = 0.f;
#pragma unroll
  for (int s = 0; s < RSLICES; ++s) {
    vmax = fmaxf(vmax, pmax[(size_t)(g * RSLICES + s) * 128 + d]);
    vs += psum[(size_t)(g * RSLICES + s) * 128 + d];
  }
  h[g * 256 + d] += vmax;
  h[g * 256 + 128 + d] += vs / (float)k;
}

// ---------------- final MLP ----------------
__global__ __launch_bounds__(256) void mlp1(const float* __restrict__ h, const float* __restrict__ W1,
    const float* __restrict__ b1, float* __restrict__ h1) {
  int o = blockIdx.x * 256 + threadIdx.x;  // 64*128
  int g = o >> 7, j = o & 127;
  const float* hp = h + g * 256;
  const float* wp = W1 + j * 256;
  float a = b1[j];
  for (int c = 0; c < 256; ++c) a += hp[c] * wp[c];
  h1[o] = fmaxf(a, 0.f);
}

__global__ __launch_bounds__(256) void mlp2(const float* __restrict__ h1, const float* __restrict__ W2,
    const float* __restrict__ b2, float* __restrict__ h2) {
  int o = blockIdx.x * 256 + threadIdx.x;  // 64*64
  int g = o >> 6, j = o & 63;
  const float* hp = h1 + g * 128;
  const float* wp = W2 + j * 128;
  float a = b2[j];
  for (int c = 0; c < 128; ++c) a += hp[c] * wp[c];
  h2[o] = fmaxf(a, 0.f);
}

__global__ __launch_bounds__(64) void mlp3(const float* __restrict__ h2, const float* __restrict__ W3,
    const float* __restrict__ b3, float* __restrict__ out) {
  int g = threadIdx.x;
  if (g >= 64) return;
  const float* hp = h2 + g * 64;
  float a = b3[0];
  for (int c = 0; c < 64; ++c) a += hp[c] * W3[c];
  out[g] = 1.f / (1.f + expf(-a));
}

extern "C" void kernel_launch(void* const* d_in, const int* in_sizes, int n_in,
                              void* d_out, int out_size, void* d_ws, size_t ws_size,
                              hipStream_t stream) {
  const int* node_ids = (const int*)d_in[0];
  const int* ei = (const int*)d_in[1];
  const float* emb = (const float*)d_in[3];
  const float* W[3][4] = {
      {(const float*)d_in[4], (const float*)d_in[5], (const float*)d_in[6], (const float*)d_in[7]},
      {(const float*)d_in[8], (const float*)d_in[9], (const float*)d_in[10], (const float*)d_in[11]},
      {(const float*)d_in[12], (const float*)d_in[13], (const float*)d_in[14], (const float*)d_in[15]}};
  const float* W1 = (const float*)d_in[16];
  const float* b1 = (const float*)d_in[17];
  const float* W2 = (const float*)d_in[18];
  const float* b2 = (const float*)d_in[19];
  const float* W3 = (const float*)d_in[20];
  const float* b3 = (const float*)d_in[21];
  float* out = (float*)d_out;

  const int E = NEDGES;
  char* ws = (char*)d_ws;
  size_t o = 0;
  auto alloc = [&](size_t bytes) { void* p = ws + o; o = (o + bytes + 255) & ~(size_t)255; return p; };
  _Float16* XH = (_Float16*)alloc((size_t)NNODES * 128 * 2);
  _Float16* MEANH = (_Float16*)alloc((size_t)NNODES * 128 * 2);
  int* ESORT = (int*)alloc((size_t)E * 4);
  int* ESORTL = (int*)alloc((size_t)E * 4);
  int* PART = (int*)alloc((size_t)GRAPHS * NSB * 2048 * 4);
  int* CURS = (int*)alloc((size_t)GRAPHS * NSB * 2048 * 4);
  int* OFFB = (int*)alloc((size_t)NNODES * 4);
  int* DEG = (int*)alloc((size_t)NNODES * 4);
  float* SC = (float*)alloc((size_t)NNODES * 4);
  float* TS = (float*)alloc((size_t)NNODES * 4);
  int* PERM = (int*)alloc((size_t)NNODES * 4);
  int* NOOA = (int*)alloc((size_t)NNODES * 4);
  int* NOOB = (int*)alloc((size_t)NNODES * 4);
  int* ORIGA = (int*)alloc((size_t)NNODES * 4);
  int* ORIGB = (int*)alloc((size_t)NNODES * 4);
  _Float16* WH0 = (_Float16*)alloc(4096 * 8 * 2);
  _Float16* WH1 = (_Float16*)alloc(4096 * 8 * 2);
  _Float16* WH2 = (_Float16*)alloc(4096 * 8 * 2);
  float* PMAX = (float*)alloc((size_t)GRAPHS * RSLICES * 128 * 4);
  float* PSUM = (float*)alloc((size_t)GRAPHS * RSLICES * 128 * 4);
  float* H = (float*)alloc(64 * 256 * 4);
  float* H1 = (float*)alloc(64 * 128 * 4);
  float* H2 = (float*)alloc(64 * 64 * 4);

  embed_kernel<<<NNODES * 16 / 256, 256, 0, stream>>>(node_ids, emb, XH);
  hipMemsetAsync(H, 0, 64 * 256 * 4, stream);
  convert_w<<<16, 256, 0, stream>>>(W[0][0], W[0][1], WH0);
  convert_w<<<16, 256, 0, stream>>>(W[1][0], W[1][1], WH1);
  convert_w<<<16, 256, 0, stream>>>(W[2][0], W[2][1], WH2);

  // layer-0 CSR (built once; layers 1/2 use remapped edge values)
  const int* src = ei;
  const int* dst = ei + E;
  csr_hist<<<GRAPHS * NSB, 1024, 0, stream>>>(src, dst, NPG, PART);
  csr_scan<<<GRAPHS, 1024, 0, stream>>>(PART, NPG, OFFB, DEG, CURS);
  csr_place<<<GRAPHS * NSB, 1024, 0, stream>>>(src, dst, NPG, CURS, ESORT);

  struct LayerP { int n, k; };                 // n = current node count; k = keep per graph
  LayerP L[3] = {{131072, 1639}, {104896, 1312}, {83968, 1050}};
  _Float16* WHs[3] = {WH0, WH1, WH2};
  int* ORIG_cur = ORIGA;   // maps current ids -> original ids (valid for li>=1)
  int* ORIG_next = ORIGB;

  for (int li = 0; li < 3; ++li) {
    int n = L[li].n, k = L[li].k;
    int np = n / 64;
    int n_new = 64 * k;
    const float *bl = W[li][2], *pw = W[li][3];

    int C = (np + 15) / 16;
    if (li == 0) {
      aggregate_kernel<<<64 * C, 256, 0, stream>>>(XH, OFFB, DEG, ESORT, MEANH, np, C);
    } else {
      remap_esort<<<E / 4 / 256, 256, 0, stream>>>(ESORT, NOOA, ESORTL, E / 4);
      aggregate_f<<<64 * C, 256, 0, stream>>>(XH, OFFB, DEG, ESORTL, ORIG_cur,
                                              MEANH, np, C);
    }
    sage_gemm<<<(n + RPB - 1) / RPB, 256, 0, stream>>>(XH, MEANH, MEANH, WHs[li], bl, pw, SC, n);
    topk_kernel<<<GRAPHS, 1024, 0, stream>>>(SC, np, k, TS, PERM, (li == 0) ? NOOA : NOOB);
    gather_kernel<<<n_new * 16 / 256, 256, 0, stream>>>(MEANH, PERM, TS, XH,
        (li == 0) ? nullptr : ORIG_cur, ORIG_next, n_new);
    { int* t = ORIG_cur; ORIG_cur = ORIG_next; ORIG_next = t; }
    readout_part<<<GRAPHS * RSLICES, 256, 0, stream>>>(XH, k, PMAX, PSUM);
    readout_comb<<<32, 256, 0, stream>>>(PMAX, PSUM, k, H);
    if (li == 1) compose_kernel<<<NNODES / 256, 256, 0, stream>>>(NOOA, NOOB, NNODES);
  }

  mlp1<<<32, 256, 0, stream>>>(H, W1, b1, H1);
  mlp2<<<16, 256, 0, stream>>>(H1, W2, b2, H2);
  mlp3<<<1, 64, 0, stream>>>(H2, W3, b3, out);
}

// Round 15
// 367.721 us; speedup vs baseline: 1.5325x; 1.0695x over previous
//
#include <hip/hip_runtime.h>
#include <hip/hip_bf16.h>
#include <float.h>

typedef _Float16 f16x8 __attribute__((ext_vector_type(8)));
typedef float f32x4 __attribute__((ext_vector_type(4)));

#define GRAPHS 64
#define NPG 2048
#define DIM 128
#define NNODES (GRAPHS * NPG)
#define NEDGES (NNODES * 16)
#define ECAP 32768   // edges per graph
#define NSB 8        // sub-blocks per graph for CSR build
#define RPB 256      // rows per block in sage_gemm

// ---------------- embed: xh[i] = (f16) emb[node_ids[i]] ----------------
__global__ __launch_bounds__(256) void embed_kernel(const int* __restrict__ ids,
    const float* __restrict__ emb, _Float16* __restrict__ xh) {
  int idx = blockIdx.x * 256 + threadIdx.x;
  int nd = idx >> 4, part = idx & 15;
  int id = ids[nd];
  const float* src = emb + (size_t)id * 128 + part * 8;
  float4 a = *(const float4*)(src);
  float4 b = *(const float4*)(src + 4);
  f16x8 o;
  o[0] = (_Float16)a.x; o[1] = (_Float16)a.y; o[2] = (_Float16)a.z; o[3] = (_Float16)a.w;
  o[4] = (_Float16)b.x; o[5] = (_Float16)b.y; o[6] = (_Float16)b.z; o[7] = (_Float16)b.w;
  *(f16x8*)(xh + (size_t)nd * 128 + part * 8) = o;
}

// ---------------- pre-convert weights to f16 in LDS-staging order -----------
__global__ __launch_bounds__(256) void convert_w(const float* __restrict__ Wl,
    const float* __restrict__ Wr, _Float16* __restrict__ wh) {
  int qq = blockIdx.x * 256 + threadIdx.x;   // 0..4095
  int ks = qq >> 9, nf = (qq >> 6) & 7, l = qq & 63;
  int ncol = nf * 16 + (l & 15);
  int k0 = (ks & 3) * 32 + ((l >> 4) << 3);
  const float* wsrc = ((ks < 4) ? Wl : Wr) + ncol * 128 + k0;
  float4 a = *(const float4*)wsrc;
  float4 b = *(const float4*)(wsrc + 4);
  f16x8 w;
  w[0] = (_Float16)a.x; w[1] = (_Float16)a.y; w[2] = (_Float16)a.z; w[3] = (_Float16)a.w;
  w[4] = (_Float16)b.x; w[5] = (_Float16)b.y; w[6] = (_Float16)b.z; w[7] = (_Float16)b.w;
  *(f16x8*)(wh + (size_t)qq * 8) = w;
}

// ---------------- CSR build (layer 0 only), 3 phases ------------------------
__global__ __launch_bounds__(1024) void csr_hist(const int* __restrict__ src,
    const int* __restrict__ dst, int np, int* __restrict__ part) {
  __shared__ int hist[2048];
  int x = blockIdx.x;
  int s = x & 7, q = x >> 3;
  int b = q & (NSB - 1), gh = q >> 3;
  int g = gh * 8 + s;
  int tid = threadIdx.x;
  for (int i = tid; i < 2048; i += 1024) hist[i] = 0;
  __syncthreads();
  int e0 = g * ECAP + b * (ECAP / NSB);
  int nodebase = g * np;
  for (int e = tid; e < ECAP / NSB; e += 1024) {
    atomicAdd(&hist[dst[e0 + e] - nodebase], 1);
  }
  __syncthreads();
  for (int i = tid; i < np; i += 1024) part[((size_t)(g * NSB + b)) * 2048 + i] = hist[i];
}

__global__ __launch_bounds__(1024) void csr_scan(const int* __restrict__ part, int np,
    int* __restrict__ offb, int* __restrict__ deg, int* __restrict__ curs) {
  __shared__ int psum[1024];
  int g = blockIdx.x, tid = threadIdx.x;
  int i0 = 2 * tid, i1 = 2 * tid + 1;
  int p0[NSB], p1[NSB];
  int c0 = 0, c1 = 0;
#pragma unroll
  for (int b = 0; b < NSB; ++b) {
    p0[b] = (i0 < np) ? part[((size_t)(g * NSB + b)) * 2048 + i0] : 0;
    p1[b] = (i1 < np) ? part[((size_t)(g * NSB + b)) * 2048 + i1] : 0;
    c0 += p0[b]; c1 += p1[b];
  }
  int pair = c0 + c1;
  psum[tid] = pair;
  for (int s = 1; s < 1024; s <<= 1) {
    __syncthreads();
    int t = (tid >= s) ? psum[tid - s] : 0;
    __syncthreads();
    psum[tid] += t;
  }
  int excl = psum[tid] - pair;
  int ebase = g * ECAP;
  int nodebase = g * np;
  if (i0 < np) {
    int off = ebase + excl;
    offb[nodebase + i0] = off;
    deg[nodebase + i0] = c0;
    int cur = off;
#pragma unroll
    for (int b = 0; b < NSB; ++b) { curs[((size_t)(g * NSB + b)) * 2048 + i0] = cur; cur += p0[b]; }
  }
  if (i1 < np) {
    int off = ebase + excl + c0;
    offb[nodebase + i1] = off;
    deg[nodebase + i1] = c1;
    int cur = off;
#pragma unroll
    for (int b = 0; b < NSB; ++b) { curs[((size_t)(g * NSB + b)) * 2048 + i1] = cur; cur += p1[b]; }
  }
}

__global__ __launch_bounds__(1024) void csr_place(const int* __restrict__ src,
    const int* __restrict__ dst, int np, const int* __restrict__ curs,
    int* __restrict__ esort) {
  __shared__ int cur[2048];
  int x = blockIdx.x;
  int s = x & 7, q = x >> 3;
  int b = q & (NSB - 1), gh = q >> 3;
  int g = gh * 8 + s;
  int tid = threadIdx.x;
  for (int i = tid; i < np; i += 1024) cur[i] = curs[((size_t)(g * NSB + b)) * 2048 + i];
  __syncthreads();
  int e0 = g * ECAP + b * (ECAP / NSB);
  int nodebase = g * np;
  for (int e = tid; e < ECAP / NSB; e += 1024) {
    int ge = e0 + e;
    int p = atomicAdd(&cur[dst[ge] - nodebase], 1);
    esort[p] = src[ge];
  }
}

// ---------------- remap edge list through pool map (streaming, 4/thread) -----
__global__ __launch_bounds__(256) void remap_esort(const int* __restrict__ esort0,
    const int* __restrict__ noo, int* __restrict__ esortl, int E4) {
  int t = blockIdx.x * 256 + threadIdx.x;
  if (t >= E4) return;
  int4 s = *(const int4*)(esort0 + t * 4);
  int4 o;
  o.x = noo[s.x]; o.y = noo[s.y]; o.z = noo[s.z]; o.w = noo[s.w];
  *(int4*)(esortl + t * 4) = o;
}

// ---------------- aggregate (layer 0): mean over incoming edges --------------
__global__ __launch_bounds__(256) void aggregate_kernel(const _Float16* __restrict__ xh,
    const int* __restrict__ offb, const int* __restrict__ deg, const int* __restrict__ esrc,
    _Float16* __restrict__ meanh, int np, int C) {
  int bid = blockIdx.x;
  int s = bid & 7, q = bid >> 3;
  int gsub = q / C, chunk = q - gsub * C;
  int g = gsub * 8 + s;
  int wave = threadIdx.x >> 6, lane = threadIdx.x & 63;
  int sub = lane >> 4, l = lane & 15;
  int local = chunk * 16 + wave * 4 + sub;
  if (local >= np) return;
  int w = g * np + local;
  int b = offb[w], c = deg[w];
  int e = b + c;
  float acc[8] = {0.f, 0.f, 0.f, 0.f, 0.f, 0.f, 0.f, 0.f};
  int i = b;
  for (; i + 4 <= e; i += 4) {
    int s0 = esrc[i], s1 = esrc[i + 1], s2 = esrc[i + 2], s3 = esrc[i + 3];
    f16x8 v0 = *(const f16x8*)(xh + (size_t)s0 * 128 + l * 8);
    f16x8 v1 = *(const f16x8*)(xh + (size_t)s1 * 128 + l * 8);
    f16x8 v2 = *(const f16x8*)(xh + (size_t)s2 * 128 + l * 8);
    f16x8 v3 = *(const f16x8*)(xh + (size_t)s3 * 128 + l * 8);
    f16x8 t = (v0 + v1) + (v2 + v3);
#pragma unroll
    for (int j = 0; j < 8; ++j) acc[j] += (float)t[j];
  }
  for (; i < e; ++i) {
    int srcn = esrc[i];
    f16x8 v = *(const f16x8*)(xh + (size_t)srcn * 128 + l * 8);
#pragma unroll
    for (int j = 0; j < 8; ++j) acc[j] += (float)v[j];
  }
  float inv = 1.f / (float)(c > 0 ? c : 1);
  f16x8 o;
#pragma unroll
  for (int j = 0; j < 8; ++j) o[j] = (_Float16)(acc[j] * inv);
  *(f16x8*)(meanh + (size_t)w * 128 + l * 8) = o;
}

// ---------------- aggregate (layers 1/2): pre-mapped edge list, -1 = dropped --
__global__ __launch_bounds__(256) void aggregate_f(const _Float16* __restrict__ xh,
    const int* __restrict__ offb0, const int* __restrict__ deg0, const int* __restrict__ esortl,
    const int* __restrict__ orig, _Float16* __restrict__ meanh, int np, int C) {
  int bid = blockIdx.x;
  int s = bid & 7, q = bid >> 3;
  int gsub = q / C, chunk = q - gsub * C;
  int g = gsub * 8 + s;
  int wave = threadIdx.x >> 6, lane = threadIdx.x & 63;
  int sub = lane >> 4, l = lane & 15;
  int local = chunk * 16 + wave * 4 + sub;
  if (local >= np) return;
  int w = g * np + local;
  int o = orig[w];
  int b = offb0[o], c0 = deg0[o];
  int e = b + c0;
  float acc[8] = {0.f, 0.f, 0.f, 0.f, 0.f, 0.f, 0.f, 0.f};
  int cnt = 0;
  const f16x8 zero = {(_Float16)0.f, (_Float16)0.f, (_Float16)0.f, (_Float16)0.f,
                      (_Float16)0.f, (_Float16)0.f, (_Float16)0.f, (_Float16)0.f};
  int i = b;
  for (; i + 4 <= e; i += 4) {
    int n0 = esortl[i], n1 = esortl[i + 1], n2 = esortl[i + 2], n3 = esortl[i + 3];
    f16x8 v0 = zero, v1 = zero, v2 = zero, v3 = zero;
    if (n0 >= 0) v0 = *(const f16x8*)(xh + (size_t)n0 * 128 + l * 8);
    if (n1 >= 0) v1 = *(const f16x8*)(xh + (size_t)n1 * 128 + l * 8);
    if (n2 >= 0) v2 = *(const f16x8*)(xh + (size_t)n2 * 128 + l * 8);
    if (n3 >= 0) v3 = *(const f16x8*)(xh + (size_t)n3 * 128 + l * 8);
    cnt += (n0 >= 0) + (n1 >= 0) + (n2 >= 0) + (n3 >= 0);
    f16x8 t = (v0 + v1) + (v2 + v3);
#pragma unroll
    for (int j = 0; j < 8; ++j) acc[j] += (float)t[j];
  }
  for (; i < e; ++i) {
    int sn = esortl[i];
    if (sn < 0) continue;
    ++cnt;
    f16x8 v = *(const f16x8*)(xh + (size_t)sn * 128 + l * 8);
#pragma unroll
    for (int j = 0; j < 8; ++j) acc[j] += (float)v[j];
  }
  float inv = 1.f / (float)(cnt > 0 ? cnt : 1);
  f16x8 ov;
#pragma unroll
  for (int j = 0; j < 8; ++j) ov[j] = (_Float16)(acc[j] * inv);
  *(f16x8*)(meanh + (size_t)w * 128 + l * 8) = ov;
}

// ---------------- fused SAGE transform + score (LDS weight stage) -------------
__global__ __launch_bounds__(256, 2) void sage_gemm(const _Float16* __restrict__ XH,
    const _Float16* MEANIN, _Float16* OUT, const _Float16* __restrict__ WH,
    const float* __restrict__ bl, const float* __restrict__ pw, float* __restrict__ sc,
    int n) {
  __shared__ _Float16 WB[4096 * 8];  // 64KB, layout [ks][nf][lane][8]
  int tid = threadIdx.x;
  for (int qq = tid; qq < 4096; qq += 256)
    *(f16x8*)(WB + qq * 8) = *(const f16x8*)(WH + (size_t)qq * 8);
  __syncthreads();
  int wave = tid >> 6, lane = tid & 63;
  int wrow0 = blockIdx.x * RPB + wave * 64;
  if (wrow0 >= n) return;
  int kb = (lane >> 4) << 3;
  int lr = lane & 15;
  f32x4 acc[4][8];
#pragma unroll
  for (int t = 0; t < 4; ++t)
#pragma unroll
    for (int nf = 0; nf < 8; ++nf) acc[t][nf] = (f32x4){0.f, 0.f, 0.f, 0.f};
#pragma unroll
  for (int ks = 0; ks < 8; ++ks) {
    const _Float16* A = (ks < 4) ? MEANIN : XH;
    const _Float16* ap = A + (size_t)(wrow0 + lr) * 128 + (ks & 3) * 32 + kb;
    f16x8 a0 = *(const f16x8*)(ap);
    f16x8 a1 = *(const f16x8*)(ap + 16 * 128);
    f16x8 a2 = *(const f16x8*)(ap + 32 * 128);
    f16x8 a3 = *(const f16x8*)(ap + 48 * 128);
#pragma unroll
    for (int nf = 0; nf < 8; ++nf) {
      f16x8 b = *(const f16x8*)(WB + ((ks * 8 + nf) * 64 + lane) * 8);
      acc[0][nf] = __builtin_amdgcn_mfma_f32_16x16x32_f16(a0, b, acc[0][nf], 0, 0, 0);
      acc[1][nf] = __builtin_amdgcn_mfma_f32_16x16x32_f16(a1, b, acc[1][nf], 0, 0, 0);
      acc[2][nf] = __builtin_amdgcn_mfma_f32_16x16x32_f16(a2, b, acc[2][nf], 0, 0, 0);
      acc[3][nf] = __builtin_amdgcn_mfma_f32_16x16x32_f16(a3, b, acc[3][nf], 0, 0, 0);
    }
  }
  float pwv[8], qn = 0.f;
#pragma unroll
  for (int nf = 0; nf < 8; ++nf) {
    pwv[nf] = pw[nf * 16 + lr];
    qn += pwv[nf] * pwv[nf];
  }
#pragma unroll
  for (int o = 1; o < 16; o <<= 1) qn += __shfl_xor(qn, o);
  float inv_n = 1.f / sqrtf(qn);
#pragma unroll
  for (int t = 0; t < 4; ++t) {
    int rbase = wrow0 + t * 16 + ((lane >> 4) << 2);
    float dot[4] = {0.f, 0.f, 0.f, 0.f};
#pragma unroll
    for (int nf = 0; nf < 8; ++nf) {
      int col = nf * 16 + lr;
      float bias = bl[col];
#pragma unroll
      for (int r = 0; r < 4; ++r) {
        float v = fmaxf(acc[t][nf][r] + bias, 0.f);
        OUT[(size_t)(rbase + r) * 128 + col] = (_Float16)v;
        dot[r] += v * pwv[nf];
      }
    }
#pragma unroll
    for (int r = 0; r < 4; ++r) {
#pragma unroll
      for (int o = 1; o < 16; o <<= 1) dot[r] += __shfl_xor(dot[r], o);
    }
    if (lr == 0) {
#pragma unroll
      for (int r = 0; r < 4; ++r) sc[rbase + r] = tanhf(dot[r] * inv_n);
    }
  }
}

// ---------------- fused top-k + gather/scale + ORIG + readout + compose -------
// one block per graph, 1024 threads. mode: 0 = write nooA (layer 0),
// 1 = compose nooA in place (layer 1), 2 = skip map output (last layer).
__global__ __launch_bounds__(1024) void topk_fused(const float* __restrict__ sc,
    int n_per, int k, const _Float16* __restrict__ meanin, _Float16* __restrict__ xh,
    int* __restrict__ nooA, const int* __restrict__ orig_in, int* __restrict__ orig_out,
    float* __restrict__ h, int mode) {
  __shared__ unsigned long long L[2048];
  __shared__ int c2n[2048];
  __shared__ float redmax[2048];   // 16 waves x 128 dims
  __shared__ float redsum[2048];
  int g = blockIdx.x;
  int tid = threadIdx.x;
  int lane = tid & 63, wave = tid >> 6;
  int i0 = wave * 128 + lane;
  int i1 = i0 + 64;
  const float* scg = sc + g * n_per;
  auto keyize = [&](int i) -> unsigned long long {
    float f = (i < n_per) ? scg[i] : -FLT_MAX;
    unsigned u = __float_as_uint(f);
    u = (u & 0x80000000u) ? ~u : (u | 0x80000000u);  // monotone float->uint map
    return ((unsigned long long)u << 32) | (unsigned)(2047 - i);
  };
  unsigned long long a = keyize(i0), b = keyize(i1);
#pragma clang loop unroll(disable)
  for (unsigned kk = 2; kk <= 2048; kk <<= 1) {
#pragma clang loop unroll(disable)
    for (unsigned j = kk >> 1; j >= 128; j >>= 1) {
      L[i0] = a; L[i1] = b;
      __syncthreads();
      unsigned long long pa = L[i0 ^ j], pb = L[i1 ^ j];
      bool dA = ((i0 & kk) == 0), lA = ((i0 & j) == 0);
      if ((dA == lA) ? (pa > a) : (pa < a)) a = pa;
      bool dB = ((i1 & kk) == 0), lB = ((i1 & j) == 0);
      if ((dB == lB) ? (pb > b) : (pb < b)) b = pb;
      __syncthreads();
    }
    if (kk >= 128) {
      bool desc = ((i0 & kk) == 0);
      if ((a < b) == desc) { unsigned long long t = a; a = b; b = t; }
    }
    unsigned jtop = (kk >> 1 < 32u) ? (kk >> 1) : 32u;
#pragma clang loop unroll(disable)
    for (unsigned j = jtop; j >= 1; j >>= 1) {
      unsigned long long oa = __shfl_xor(a, (int)j);
      unsigned long long ob = __shfl_xor(b, (int)j);
      bool low = ((lane & j) == 0);
      bool dA = ((i0 & kk) == 0);
      if ((dA == low) ? (oa > a) : (oa < a)) a = oa;
      bool dB = ((i1 & kk) == 0);
      if ((dB == low) ? (ob > b) : (ob < b)) b = ob;
    }
  }
  // rank table to LDS + pool-map output
  L[i0] = a; L[i1] = b;
  int orig_a = 2047 - (int)(a & 0xFFFFFFFFu);
  int orig_b = 2047 - (int)(b & 0xFFFFFFFFu);
  if (mode == 0) {
    if (orig_a < n_per) nooA[g * n_per + orig_a] = (i0 < k) ? g * k + i0 : -1;
    if (orig_b < n_per) nooA[g * n_per + orig_b] = (i1 < k) ? g * k + i1 : -1;
  } else if (mode == 1) {
    if (orig_a < n_per) c2n[orig_a] = (i0 < k) ? g * k + i0 : -1;
    if (orig_b < n_per) c2n[orig_b] = (i1 < k) ? g * k + i1 : -1;
  }
  __syncthreads();
  if (mode == 1) {
    for (int o2 = tid; o2 < NPG; o2 += 1024) {
      int a0 = nooA[g * NPG + o2];
      nooA[g * NPG + o2] = (a0 >= 0) ? c2n[a0 - g * n_per] : -1;
    }
  }
  // gather + scale + readout partials: 16-lane group per row, 64 rows/iter
  int grp = tid >> 4, l8 = tid & 15;
  float vmax[8], vsum[8];
#pragma unroll
  for (int j = 0; j < 8; ++j) { vmax[j] = -FLT_MAX; vsum[j] = 0.f; }
  for (int r = grp; r < k; r += 64) {
    unsigned long long key = L[r];
    int orig = 2047 - (int)(key & 0xFFFFFFFFu);
    int p = g * n_per + orig;
    float score = scg[orig];
    f16x8 v = *(const f16x8*)(meanin + (size_t)p * 128 + l8 * 8);
    f16x8 ovv;
#pragma unroll
    for (int j = 0; j < 8; ++j) {
      float val = (float)v[j] * score;
      ovv[j] = (_Float16)val;
      vmax[j] = fmaxf(vmax[j], val);
      vsum[j] += val;
    }
    *(f16x8*)(xh + (size_t)(g * k + r) * 128 + l8 * 8) = ovv;
    if (l8 == 0) orig_out[g * k + r] = orig_in ? orig_in[p] : p;
  }
  // reduce the 4 row-groups within each wave (lane xor 16, 32)
#pragma unroll
  for (int j = 0; j < 8; ++j) {
    vmax[j] = fmaxf(vmax[j], __shfl_xor(vmax[j], 16));
    vmax[j] = fmaxf(vmax[j], __shfl_xor(vmax[j], 32));
    vsum[j] += __shfl_xor(vsum[j], 16);
    vsum[j] += __shfl_xor(vsum[j], 32);
  }
  if ((lane >> 4) == 0) {
#pragma unroll
    for (int j = 0; j < 8; ++j) {
      redmax[wave * 128 + l8 * 8 + j] = vmax[j];
      redsum[wave * 128 + l8 * 8 + j] = vsum[j];
    }
  }
  __syncthreads();
  if (tid < 128) {
    float m = -FLT_MAX, s2 = 0.f;
#pragma unroll
    for (int wv = 0; wv < 16; ++wv) {
      m = fmaxf(m, redmax[wv * 128 + tid]);
      s2 += redsum[wv * 128 + tid];
    }
    h[g * 256 + tid] += m;
    h[g * 256 + 128 + tid] += s2 / (float)k;
  }
}

// ---------------- final MLP ----------------
__global__ __launch_bounds__(256) void mlp1(const float* __restrict__ h, const float* __restrict__ W1,
    const float* __restrict__ b1, float* __restrict__ h1) {
  int o = blockIdx.x * 256 + threadIdx.x;  // 64*128
  int g = o >> 7, j = o & 127;
  const float* hp = h + g * 256;
  const float* wp = W1 + j * 256;
  float a = b1[j];
  for (int c = 0; c < 256; ++c) a += hp[c] * wp[c];
  h1[o] = fmaxf(a, 0.f);
}

__global__ __launch_bounds__(256) void mlp2(const float* __restrict__ h1, const float* __restrict__ W2,
    const float* __restrict__ b2, float* __restrict__ h2) {
  int o = blockIdx.x * 256 + threadIdx.x;  // 64*64
  int g = o >> 6, j = o & 63;
  const float* hp = h1 + g * 128;
  const float* wp = W2 + j * 128;
  float a = b2[j];
  for (int c = 0; c < 128; ++c) a += hp[c] * wp[c];
  h2[o] = fmaxf(a, 0.f);
}

__global__ __launch_bounds__(64) void mlp3(const float* __restrict__ h2, const float* __restrict__ W3,
    const float* __restrict__ b3, float* __restrict__ out) {
  int g = threadIdx.x;
  if (g >= 64) return;
  const float* hp = h2 + g * 64;
  float a = b3[0];
  for (int c = 0; c < 64; ++c) a += hp[c] * W3[c];
  out[g] = 1.f / (1.f + expf(-a));
}

extern "C" void kernel_launch(void* const* d_in, const int* in_sizes, int n_in,
                              void* d_out, int out_size, void* d_ws, size_t ws_size,
                              hipStream_t stream) {
  const int* node_ids = (const int*)d_in[0];
  const int* ei = (const int*)d_in[1];
  const float* emb = (const float*)d_in[3];
  const float* W[3][4] = {
      {(const float*)d_in[4], (const float*)d_in[5], (const float*)d_in[6], (const float*)d_in[7]},
      {(const float*)d_in[8], (const float*)d_in[9], (const float*)d_in[10], (const float*)d_in[11]},
      {(const float*)d_in[12], (const float*)d_in[13], (const float*)d_in[14], (const float*)d_in[15]}};
  const float* W1 = (const float*)d_in[16];
  const float* b1 = (const float*)d_in[17];
  const float* W2 = (const float*)d_in[18];
  const float* b2 = (const float*)d_in[19];
  const float* W3 = (const float*)d_in[20];
  const float* b3 = (const float*)d_in[21];
  float* out = (float*)d_out;

  const int E = NEDGES;
  char* ws = (char*)d_ws;
  size_t o = 0;
  auto alloc = [&](size_t bytes) { void* p = ws + o; o = (o + bytes + 255) & ~(size_t)255; return p; };
  _Float16* XH = (_Float16*)alloc((size_t)NNODES * 128 * 2);
  _Float16* MEANH = (_Float16*)alloc((size_t)NNODES * 128 * 2);
  int* ESORT = (int*)alloc((size_t)E * 4);
  int* ESORTL = (int*)alloc((size_t)E * 4);
  int* PART = (int*)alloc((size_t)GRAPHS * NSB * 2048 * 4);
  int* CURS = (int*)alloc((size_t)GRAPHS * NSB * 2048 * 4);
  int* OFFB = (int*)alloc((size_t)NNODES * 4);
  int* DEG = (int*)alloc((size_t)NNODES * 4);
  float* SC = (float*)alloc((size_t)NNODES * 4);
  int* NOOA = (int*)alloc((size_t)NNODES * 4);
  int* ORIGA = (int*)alloc((size_t)NNODES * 4);
  int* ORIGB = (int*)alloc((size_t)NNODES * 4);
  _Float16* WH0 = (_Float16*)alloc(4096 * 8 * 2);
  _Float16* WH1 = (_Float16*)alloc(4096 * 8 * 2);
  _Float16* WH2 = (_Float16*)alloc(4096 * 8 * 2);
  float* H = (float*)alloc(64 * 256 * 4);
  float* H1 = (float*)alloc(64 * 128 * 4);
  float* H2 = (float*)alloc(64 * 64 * 4);

  embed_kernel<<<NNODES * 16 / 256, 256, 0, stream>>>(node_ids, emb, XH);
  hipMemsetAsync(H, 0, 64 * 256 * 4, stream);
  convert_w<<<16, 256, 0, stream>>>(W[0][0], W[0][1], WH0);
  convert_w<<<16, 256, 0, stream>>>(W[1][0], W[1][1], WH1);
  convert_w<<<16, 256, 0, stream>>>(W[2][0], W[2][1], WH2);

  // layer-0 CSR (built once; layers 1/2 use remapped edge values)
  const int* src = ei;
  const int* dst = ei + E;
  csr_hist<<<GRAPHS * NSB, 1024, 0, stream>>>(src, dst, NPG, PART);
  csr_scan<<<GRAPHS, 1024, 0, stream>>>(PART, NPG, OFFB, DEG, CURS);
  csr_place<<<GRAPHS * NSB, 1024, 0, stream>>>(src, dst, NPG, CURS, ESORT);

  struct LayerP { int n, k; };                 // n = current node count; k = keep per graph
  LayerP L[3] = {{131072, 1639}, {104896, 1312}, {83968, 1050}};
  _Float16* WHs[3] = {WH0, WH1, WH2};
  int* ORIG_cur = ORIGA;   // maps current ids -> original ids (valid for li>=1)
  int* ORIG_next = ORIGB;

  for (int li = 0; li < 3; ++li) {
    int n = L[li].n, k = L[li].k;
    int np = n / 64;
    const float *bl = W[li][2], *pw = W[li][3];

    int C = (np + 15) / 16;
    if (li == 0) {
      aggregate_kernel<<<64 * C, 256, 0, stream>>>(XH, OFFB, DEG, ESORT, MEANH, np, C);
    } else {
      remap_esort<<<E / 4 / 256, 256, 0, stream>>>(ESORT, NOOA, ESORTL, E / 4);
      aggregate_f<<<64 * C, 256, 0, stream>>>(XH, OFFB, DEG, ESORTL, ORIG_cur,
                                              MEANH, np, C);
    }
    sage_gemm<<<(n + RPB - 1) / RPB, 256, 0, stream>>>(XH, MEANH, MEANH, WHs[li], bl, pw, SC, n);
    topk_fused<<<GRAPHS, 1024, 0, stream>>>(SC, np, k, MEANH, XH, NOOA,
        (li == 0) ? nullptr : ORIG_cur, ORIG_next, H, li);
    { int* t = ORIG_cur; ORIG_cur = ORIG_next; ORIG_next = t; }
  }

  mlp1<<<32, 256, 0, stream>>>(H, W1, b1, H1);
  mlp2<<<16, 256, 0, stream>>>(H1, W2, b2, H2);
  mlp3<<<1, 64, 0, stream>>>(H2, W3, b3, out);
}

// Round 16
// 363.411 us; speedup vs baseline: 1.5507x; 1.0119x over previous
//
#include <hip/hip_runtime.h>
#include <hip/hip_bf16.h>
#include <float.h>

typedef _Float16 f16x8 __attribute__((ext_vector_type(8)));
typedef float f32x4 __attribute__((ext_vector_type(4)));

#define GRAPHS 64
#define NPG 2048
#define DIM 128
#define NNODES (GRAPHS * NPG)
#define NEDGES (NNODES * 16)
#define ECAP 32768   // edges per graph
#define NSB 8        // sub-blocks per graph for CSR build
#define RSL 8        // readout slices per graph
#define RPB 256      // rows per block in sage_gemm

// ---------------- embed: xh[i] = (f16) emb[node_ids[i]] ----------------
__global__ __launch_bounds__(256) void embed_kernel(const int* __restrict__ ids,
    const float* __restrict__ emb, _Float16* __restrict__ xh) {
  int idx = blockIdx.x * 256 + threadIdx.x;
  int nd = idx >> 4, part = idx & 15;
  int id = ids[nd];
  const float* src = emb + (size_t)id * 128 + part * 8;
  float4 a = *(const float4*)(src);
  float4 b = *(const float4*)(src + 4);
  f16x8 o;
  o[0] = (_Float16)a.x; o[1] = (_Float16)a.y; o[2] = (_Float16)a.z; o[3] = (_Float16)a.w;
  o[4] = (_Float16)b.x; o[5] = (_Float16)b.y; o[6] = (_Float16)b.z; o[7] = (_Float16)b.w;
  *(f16x8*)(xh + (size_t)nd * 128 + part * 8) = o;
}

// ---------------- pre-convert weights to f16 in LDS-staging order -----------
__global__ __launch_bounds__(256) void convert_w(const float* __restrict__ Wl,
    const float* __restrict__ Wr, _Float16* __restrict__ wh) {
  int qq = blockIdx.x * 256 + threadIdx.x;   // 0..4095
  int ks = qq >> 9, nf = (qq >> 6) & 7, l = qq & 63;
  int ncol = nf * 16 + (l & 15);
  int k0 = (ks & 3) * 32 + ((l >> 4) << 3);
  const float* wsrc = ((ks < 4) ? Wl : Wr) + ncol * 128 + k0;
  float4 a = *(const float4*)wsrc;
  float4 b = *(const float4*)(wsrc + 4);
  f16x8 w;
  w[0] = (_Float16)a.x; w[1] = (_Float16)a.y; w[2] = (_Float16)a.z; w[3] = (_Float16)a.w;
  w[4] = (_Float16)b.x; w[5] = (_Float16)b.y; w[6] = (_Float16)b.z; w[7] = (_Float16)b.w;
  *(f16x8*)(wh + (size_t)qq * 8) = w;
}

// ---------------- CSR build (layer 0 only), 3 phases ------------------------
__global__ __launch_bounds__(1024) void csr_hist(const int* __restrict__ src,
    const int* __restrict__ dst, int np, int* __restrict__ part) {
  __shared__ int hist[2048];
  int x = blockIdx.x;
  int s = x & 7, q = x >> 3;
  int b = q & (NSB - 1), gh = q >> 3;
  int g = gh * 8 + s;
  int tid = threadIdx.x;
  for (int i = tid; i < 2048; i += 1024) hist[i] = 0;
  __syncthreads();
  int e0 = g * ECAP + b * (ECAP / NSB);
  int nodebase = g * np;
  for (int e = tid; e < ECAP / NSB; e += 1024) {
    atomicAdd(&hist[dst[e0 + e] - nodebase], 1);
  }
  __syncthreads();
  for (int i = tid; i < np; i += 1024) part[((size_t)(g * NSB + b)) * 2048 + i] = hist[i];
}

__global__ __launch_bounds__(1024) void csr_scan(const int* __restrict__ part, int np,
    int* __restrict__ offb, int* __restrict__ deg, int* __restrict__ curs) {
  __shared__ int psum[1024];
  int g = blockIdx.x, tid = threadIdx.x;
  int i0 = 2 * tid, i1 = 2 * tid + 1;
  int p0[NSB], p1[NSB];
  int c0 = 0, c1 = 0;
#pragma unroll
  for (int b = 0; b < NSB; ++b) {
    p0[b] = (i0 < np) ? part[((size_t)(g * NSB + b)) * 2048 + i0] : 0;
    p1[b] = (i1 < np) ? part[((size_t)(g * NSB + b)) * 2048 + i1] : 0;
    c0 += p0[b]; c1 += p1[b];
  }
  int pair = c0 + c1;
  psum[tid] = pair;
  for (int s = 1; s < 1024; s <<= 1) {
    __syncthreads();
    int t = (tid >= s) ? psum[tid - s] : 0;
    __syncthreads();
    psum[tid] += t;
  }
  int excl = psum[tid] - pair;
  int ebase = g * ECAP;
  int nodebase = g * np;
  if (i0 < np) {
    int off = ebase + excl;
    offb[nodebase + i0] = off;
    deg[nodebase + i0] = c0;
    int cur = off;
#pragma unroll
    for (int b = 0; b < NSB; ++b) { curs[((size_t)(g * NSB + b)) * 2048 + i0] = cur; cur += p0[b]; }
  }
  if (i1 < np) {
    int off = ebase + excl + c0;
    offb[nodebase + i1] = off;
    deg[nodebase + i1] = c1;
    int cur = off;
#pragma unroll
    for (int b = 0; b < NSB; ++b) { curs[((size_t)(g * NSB + b)) * 2048 + i1] = cur; cur += p1[b]; }
  }
}

__global__ __launch_bounds__(1024) void csr_place(const int* __restrict__ src,
    const int* __restrict__ dst, int np, const int* __restrict__ curs,
    int* __restrict__ esort) {
  __shared__ int cur[2048];
  int x = blockIdx.x;
  int s = x & 7, q = x >> 3;
  int b = q & (NSB - 1), gh = q >> 3;
  int g = gh * 8 + s;
  int tid = threadIdx.x;
  for (int i = tid; i < np; i += 1024) cur[i] = curs[((size_t)(g * NSB + b)) * 2048 + i];
  __syncthreads();
  int e0 = g * ECAP + b * (ECAP / NSB);
  int nodebase = g * np;
  for (int e = tid; e < ECAP / NSB; e += 1024) {
    int ge = e0 + e;
    int p = atomicAdd(&cur[dst[ge] - nodebase], 1);
    esort[p] = src[ge];
  }
}

// ---------------- remap edge list through pool map (streaming, 4/thread) -----
__global__ __launch_bounds__(256) void remap_esort(const int* __restrict__ esort0,
    const int* __restrict__ noo, int* __restrict__ esortl, int E4) {
  int t = blockIdx.x * 256 + threadIdx.x;
  if (t >= E4) return;
  int4 s = *(const int4*)(esort0 + t * 4);
  int4 o;
  o.x = noo[s.x]; o.y = noo[s.y]; o.z = noo[s.z]; o.w = noo[s.w];
  *(int4*)(esortl + t * 4) = o;
}

// ---------------- aggregate (layer 0): mean over incoming edges --------------
__global__ __launch_bounds__(256) void aggregate_kernel(const _Float16* __restrict__ xh,
    const int* __restrict__ offb, const int* __restrict__ deg, const int* __restrict__ esrc,
    _Float16* __restrict__ meanh, int np, int C) {
  int bid = blockIdx.x;
  int s = bid & 7, q = bid >> 3;
  int gsub = q / C, chunk = q - gsub * C;
  int g = gsub * 8 + s;
  int wave = threadIdx.x >> 6, lane = threadIdx.x & 63;
  int sub = lane >> 4, l = lane & 15;
  int local = chunk * 16 + wave * 4 + sub;
  if (local >= np) return;
  int w = g * np + local;
  int b = offb[w], c = deg[w];
  int e = b + c;
  float acc[8] = {0.f, 0.f, 0.f, 0.f, 0.f, 0.f, 0.f, 0.f};
  int i = b;
  for (; i + 4 <= e; i += 4) {
    int s0 = esrc[i], s1 = esrc[i + 1], s2 = esrc[i + 2], s3 = esrc[i + 3];
    f16x8 v0 = *(const f16x8*)(xh + (size_t)s0 * 128 + l * 8);
    f16x8 v1 = *(const f16x8*)(xh + (size_t)s1 * 128 + l * 8);
    f16x8 v2 = *(const f16x8*)(xh + (size_t)s2 * 128 + l * 8);
    f16x8 v3 = *(const f16x8*)(xh + (size_t)s3 * 128 + l * 8);
    f16x8 t = (v0 + v1) + (v2 + v3);
#pragma unroll
    for (int j = 0; j < 8; ++j) acc[j] += (float)t[j];
  }
  for (; i < e; ++i) {
    int srcn = esrc[i];
    f16x8 v = *(const f16x8*)(xh + (size_t)srcn * 128 + l * 8);
#pragma unroll
    for (int j = 0; j < 8; ++j) acc[j] += (float)v[j];
  }
  float inv = 1.f / (float)(c > 0 ? c : 1);
  f16x8 o;
#pragma unroll
  for (int j = 0; j < 8; ++j) o[j] = (_Float16)(acc[j] * inv);
  *(f16x8*)(meanh + (size_t)w * 128 + l * 8) = o;
}

// ---------------- aggregate (layers 1/2): pre-mapped edge list, -1 = dropped --
__global__ __launch_bounds__(256) void aggregate_f(const _Float16* __restrict__ xh,
    const int* __restrict__ offb0, const int* __restrict__ deg0, const int* __restrict__ esortl,
    const int* __restrict__ orig, _Float16* __restrict__ meanh, int np, int C) {
  int bid = blockIdx.x;
  int s = bid & 7, q = bid >> 3;
  int gsub = q / C, chunk = q - gsub * C;
  int g = gsub * 8 + s;
  int wave = threadIdx.x >> 6, lane = threadIdx.x & 63;
  int sub = lane >> 4, l = lane & 15;
  int local = chunk * 16 + wave * 4 + sub;
  if (local >= np) return;
  int w = g * np + local;
  int o = orig[w];
  int b = offb0[o], c0 = deg0[o];
  int e = b + c0;
  float acc[8] = {0.f, 0.f, 0.f, 0.f, 0.f, 0.f, 0.f, 0.f};
  int cnt = 0;
  const f16x8 zero = {(_Float16)0.f, (_Float16)0.f, (_Float16)0.f, (_Float16)0.f,
                      (_Float16)0.f, (_Float16)0.f, (_Float16)0.f, (_Float16)0.f};
  int i = b;
  for (; i + 4 <= e; i += 4) {
    int n0 = esortl[i], n1 = esortl[i + 1], n2 = esortl[i + 2], n3 = esortl[i + 3];
    f16x8 v0 = zero, v1 = zero, v2 = zero, v3 = zero;
    if (n0 >= 0) v0 = *(const f16x8*)(xh + (size_t)n0 * 128 + l * 8);
    if (n1 >= 0) v1 = *(const f16x8*)(xh + (size_t)n1 * 128 + l * 8);
    if (n2 >= 0) v2 = *(const f16x8*)(xh + (size_t)n2 * 128 + l * 8);
    if (n3 >= 0) v3 = *(const f16x8*)(xh + (size_t)n3 * 128 + l * 8);
    cnt += (n0 >= 0) + (n1 >= 0) + (n2 >= 0) + (n3 >= 0);
    f16x8 t = (v0 + v1) + (v2 + v3);
#pragma unroll
    for (int j = 0; j < 8; ++j) acc[j] += (float)t[j];
  }
  for (; i < e; ++i) {
    int sn = esortl[i];
    if (sn < 0) continue;
    ++cnt;
    f16x8 v = *(const f16x8*)(xh + (size_t)sn * 128 + l * 8);
#pragma unroll
    for (int j = 0; j < 8; ++j) acc[j] += (float)v[j];
  }
  float inv = 1.f / (float)(cnt > 0 ? cnt : 1);
  f16x8 ov;
#pragma unroll
  for (int j = 0; j < 8; ++j) ov[j] = (_Float16)(acc[j] * inv);
  *(f16x8*)(meanh + (size_t)w * 128 + l * 8) = ov;
}

// ---------------- fused SAGE transform + score (LDS weight stage) -------------
__global__ __launch_bounds__(256, 2) void sage_gemm(const _Float16* __restrict__ XH,
    const _Float16* MEANIN, _Float16* OUT, const _Float16* __restrict__ WH,
    const float* __restrict__ bl, const float* __restrict__ pw, float* __restrict__ sc,
    int n) {
  __shared__ _Float16 WB[4096 * 8];  // 64KB, layout [ks][nf][lane][8]
  int tid = threadIdx.x;
  for (int qq = tid; qq < 4096; qq += 256)
    *(f16x8*)(WB + qq * 8) = *(const f16x8*)(WH + (size_t)qq * 8);
  __syncthreads();
  int wave = tid >> 6, lane = tid & 63;
  int wrow0 = blockIdx.x * RPB + wave * 64;
  if (wrow0 >= n) return;
  int kb = (lane >> 4) << 3;
  int lr = lane & 15;
  f32x4 acc[4][8];
#pragma unroll
  for (int t = 0; t < 4; ++t)
#pragma unroll
    for (int nf = 0; nf < 8; ++nf) acc[t][nf] = (f32x4){0.f, 0.f, 0.f, 0.f};
#pragma unroll
  for (int ks = 0; ks < 8; ++ks) {
    const _Float16* A = (ks < 4) ? MEANIN : XH;
    const _Float16* ap = A + (size_t)(wrow0 + lr) * 128 + (ks & 3) * 32 + kb;
    f16x8 a0 = *(const f16x8*)(ap);
    f16x8 a1 = *(const f16x8*)(ap + 16 * 128);
    f16x8 a2 = *(const f16x8*)(ap + 32 * 128);
    f16x8 a3 = *(const f16x8*)(ap + 48 * 128);
#pragma unroll
    for (int nf = 0; nf < 8; ++nf) {
      f16x8 b = *(const f16x8*)(WB + ((ks * 8 + nf) * 64 + lane) * 8);
      acc[0][nf] = __builtin_amdgcn_mfma_f32_16x16x32_f16(a0, b, acc[0][nf], 0, 0, 0);
      acc[1][nf] = __builtin_amdgcn_mfma_f32_16x16x32_f16(a1, b, acc[1][nf], 0, 0, 0);
      acc[2][nf] = __builtin_amdgcn_mfma_f32_16x16x32_f16(a2, b, acc[2][nf], 0, 0, 0);
      acc[3][nf] = __builtin_amdgcn_mfma_f32_16x16x32_f16(a3, b, acc[3][nf], 0, 0, 0);
    }
  }
  float pwv[8], qn = 0.f;
#pragma unroll
  for (int nf = 0; nf < 8; ++nf) {
    pwv[nf] = pw[nf * 16 + lr];
    qn += pwv[nf] * pwv[nf];
  }
#pragma unroll
  for (int o = 1; o < 16; o <<= 1) qn += __shfl_xor(qn, o);
  float inv_n = 1.f / sqrtf(qn);
#pragma unroll
  for (int t = 0; t < 4; ++t) {
    int rbase = wrow0 + t * 16 + ((lane >> 4) << 2);
    float dot[4] = {0.f, 0.f, 0.f, 0.f};
#pragma unroll
    for (int nf = 0; nf < 8; ++nf) {
      int col = nf * 16 + lr;
      float bias = bl[col];
#pragma unroll
      for (int r = 0; r < 4; ++r) {
        float v = fmaxf(acc[t][nf][r] + bias, 0.f);
        OUT[(size_t)(rbase + r) * 128 + col] = (_Float16)v;
        dot[r] += v * pwv[nf];
      }
    }
#pragma unroll
    for (int r = 0; r < 4; ++r) {
#pragma unroll
      for (int o = 1; o < 16; o <<= 1) dot[r] += __shfl_xor(dot[r], o);
    }
    if (lr == 0) {
#pragma unroll
      for (int r = 0; r < 4; ++r) sc[rbase + r] = tanhf(dot[r] * inv_n);
    }
  }
}

// ---------------- top-k sort: bitonic + NOO map + rank table -----------------
// one block per graph. mode: 0 = write nooA, 1 = compose nooA, 2 = skip.
__global__ __launch_bounds__(1024) void topk_sort(const float* __restrict__ sc,
    int n_per, int k, int* __restrict__ nooA, int* __restrict__ rankt, int mode) {
  __shared__ unsigned long long L[2048];
  __shared__ int c2n[2048];
  int g = blockIdx.x;
  int tid = threadIdx.x;
  int lane = tid & 63, wave = tid >> 6;
  int i0 = wave * 128 + lane;
  int i1 = i0 + 64;
  const float* scg = sc + g * n_per;
  auto keyize = [&](int i) -> unsigned long long {
    float f = (i < n_per) ? scg[i] : -FLT_MAX;
    unsigned u = __float_as_uint(f);
    u = (u & 0x80000000u) ? ~u : (u | 0x80000000u);  // monotone float->uint map
    return ((unsigned long long)u << 32) | (unsigned)(2047 - i);
  };
  unsigned long long a = keyize(i0), b = keyize(i1);
#pragma clang loop unroll(disable)
  for (unsigned kk = 2; kk <= 2048; kk <<= 1) {
#pragma clang loop unroll(disable)
    for (unsigned j = kk >> 1; j >= 128; j >>= 1) {
      L[i0] = a; L[i1] = b;
      __syncthreads();
      unsigned long long pa = L[i0 ^ j], pb = L[i1 ^ j];
      bool dA = ((i0 & kk) == 0), lA = ((i0 & j) == 0);
      if ((dA == lA) ? (pa > a) : (pa < a)) a = pa;
      bool dB = ((i1 & kk) == 0), lB = ((i1 & j) == 0);
      if ((dB == lB) ? (pb > b) : (pb < b)) b = pb;
      __syncthreads();
    }
    if (kk >= 128) {
      bool desc = ((i0 & kk) == 0);
      if ((a < b) == desc) { unsigned long long t = a; a = b; b = t; }
    }
    unsigned jtop = (kk >> 1 < 32u) ? (kk >> 1) : 32u;
#pragma clang loop unroll(disable)
    for (unsigned j = jtop; j >= 1; j >>= 1) {
      unsigned long long oa = __shfl_xor(a, (int)j);
      unsigned long long ob = __shfl_xor(b, (int)j);
      bool low = ((lane & j) == 0);
      bool dA = ((i0 & kk) == 0);
      if ((dA == low) ? (oa > a) : (oa < a)) a = oa;
      bool dB = ((i1 & kk) == 0);
      if ((dB == low) ? (ob > b) : (ob < b)) b = ob;
    }
  }
  int orig_a = 2047 - (int)(a & 0xFFFFFFFFu);
  int orig_b = 2047 - (int)(b & 0xFFFFFFFFu);
  if (i0 < k) rankt[g * NPG + i0] = orig_a;
  if (i1 < k) rankt[g * NPG + i1] = orig_b;
  if (mode == 0) {
    if (orig_a < n_per) nooA[g * n_per + orig_a] = (i0 < k) ? g * k + i0 : -1;
    if (orig_b < n_per) nooA[g * n_per + orig_b] = (i1 < k) ? g * k + i1 : -1;
  } else if (mode == 1) {
    if (orig_a < n_per) c2n[orig_a] = (i0 < k) ? g * k + i0 : -1;
    if (orig_b < n_per) c2n[orig_b] = (i1 < k) ? g * k + i1 : -1;
    __syncthreads();
    for (int o2 = tid; o2 < NPG; o2 += 1024) {
      int a0 = nooA[g * NPG + o2];
      nooA[g * NPG + o2] = (a0 >= 0) ? c2n[a0 - g * n_per] : -1;
    }
  }
}

// ---------------- top-k tail: gather+scale+XH write+ORIG+readout partials -----
// grid = GRAPHS * RSL blocks, 256 threads; block handles rows [r0, r1) of k.
__global__ __launch_bounds__(256) void topk_tail(const float* __restrict__ sc,
    const int* __restrict__ rankt, int n_per, int k, const _Float16* __restrict__ meanin,
    _Float16* __restrict__ xh, const int* __restrict__ orig_in, int* __restrict__ orig_out,
    float* __restrict__ pmax, float* __restrict__ psum) {
  int g = blockIdx.x >> 3;
  int slice = blockIdx.x & (RSL - 1);
  int rpb = (k + RSL - 1) / RSL;
  int r0 = slice * rpb;
  int r1 = r0 + rpb; if (r1 > k) r1 = k;
  const float* scg = sc + g * n_per;
  int grp = threadIdx.x >> 4, l8 = threadIdx.x & 15;
  float vmax[8], vsum[8];
#pragma unroll
  for (int j = 0; j < 8; ++j) { vmax[j] = -FLT_MAX; vsum[j] = 0.f; }
  for (int r = r0 + grp; r < r1; r += 16) {
    int orig = rankt[g * NPG + r];
    int p = g * n_per + orig;
    float score = scg[orig];
    f16x8 v = *(const f16x8*)(meanin + (size_t)p * 128 + l8 * 8);
    f16x8 ovv;
#pragma unroll
    for (int j = 0; j < 8; ++j) {
      float val = (float)v[j] * score;
      ovv[j] = (_Float16)val;
      vmax[j] = fmaxf(vmax[j], val);
      vsum[j] += val;
    }
    *(f16x8*)(xh + (size_t)(g * k + r) * 128 + l8 * 8) = ovv;
    if (l8 == 0) orig_out[g * k + r] = orig_in ? orig_in[p] : p;
  }
  // reduce 16 groups: lane-xor within wave (16,32), then LDS across 4 waves
  __shared__ float smax[4 * 128], ssum[4 * 128];
  int lane = threadIdx.x & 63, wave = threadIdx.x >> 6;
#pragma unroll
  for (int j = 0; j < 8; ++j) {
    vmax[j] = fmaxf(vmax[j], __shfl_xor(vmax[j], 16));
    vmax[j] = fmaxf(vmax[j], __shfl_xor(vmax[j], 32));
    vsum[j] += __shfl_xor(vsum[j], 16);
    vsum[j] += __shfl_xor(vsum[j], 32);
  }
  if ((lane >> 4) == 0) {
#pragma unroll
    for (int j = 0; j < 8; ++j) {
      smax[wave * 128 + l8 * 8 + j] = vmax[j];
      ssum[wave * 128 + l8 * 8 + j] = vsum[j];
    }
  }
  __syncthreads();
  if (threadIdx.x < 128) {
    int d = threadIdx.x;
    float m = fmaxf(fmaxf(smax[d], smax[128 + d]), fmaxf(smax[256 + d], smax[384 + d]));
    float s2 = ssum[d] + ssum[128 + d] + ssum[256 + d] + ssum[384 + d];
    pmax[(size_t)(g * RSL + slice) * 128 + d] = m;
    psum[(size_t)(g * RSL + slice) * 128 + d] = s2;
  }
}

// ---------------- readout combine: h[g] += [max, mean] ----------------
__global__ __launch_bounds__(256) void readout_comb(const float* __restrict__ pmax,
    const float* __restrict__ psum, int k, float* __restrict__ h) {
  int idx = blockIdx.x * 256 + threadIdx.x;  // 64*128
  int g = idx >> 7, d = idx & 127;
  float vmax = -FLT_MAX, vs = 0.f;
#pragma unroll
  for (int s = 0; s < RSL; ++s) {
    vmax = fmaxf(vmax, pmax[(size_t)(g * RSL + s) * 128 + d]);
    vs += psum[(size_t)(g * RSL + s) * 128 + d];
  }
  h[g * 256 + d] += vmax;
  h[g * 256 + 128 + d] += vs / (float)k;
}

// ---------------- final MLP ----------------
__global__ __launch_bounds__(256) void mlp1(const float* __restrict__ h, const float* __restrict__ W1,
    const float* __restrict__ b1, float* __restrict__ h1) {
  int o = blockIdx.x * 256 + threadIdx.x;  // 64*128
  int g = o >> 7, j = o & 127;
  const float* hp = h + g * 256;
  const float* wp = W1 + j * 256;
  float a = b1[j];
  for (int c = 0; c < 256; ++c) a += hp[c] * wp[c];
  h1[o] = fmaxf(a, 0.f);
}

__global__ __launch_bounds__(256) void mlp2(const float* __restrict__ h1, const float* __restrict__ W2,
    const float* __restrict__ b2, float* __restrict__ h2) {
  int o = blockIdx.x * 256 + threadIdx.x;  // 64*64
  int g = o >> 6, j = o & 63;
  const float* hp = h1 + g * 128;
  const float* wp = W2 + j * 128;
  float a = b2[j];
  for (int c = 0; c < 128; ++c) a += hp[c] * wp[c];
  h2[o] = fmaxf(a, 0.f);
}

__global__ __launch_bounds__(64) void mlp3(const float* __restrict__ h2, const float* __restrict__ W3,
    const float* __restrict__ b3, float* __restrict__ out) {
  int g = threadIdx.x;
  if (g >= 64) return;
  const float* hp = h2 + g * 64;
  float a = b3[0];
  for (int c = 0; c < 64; ++c) a += hp[c] * W3[c];
  out[g] = 1.f / (1.f + expf(-a));
}

extern "C" void kernel_launch(void* const* d_in, const int* in_sizes, int n_in,
                              void* d_out, int out_size, void* d_ws, size_t ws_size,
                              hipStream_t stream) {
  const int* node_ids = (const int*)d_in[0];
  const int* ei = (const int*)d_in[1];
  const float* emb = (const float*)d_in[3];
  const float* W[3][4] = {
      {(const float*)d_in[4], (const float*)d_in[5], (const float*)d_in[6], (const float*)d_in[7]},
      {(const float*)d_in[8], (const float*)d_in[9], (const float*)d_in[10], (const float*)d_in[11]},
      {(const float*)d_in[12], (const float*)d_in[13], (const float*)d_in[14], (const float*)d_in[15]}};
  const float* W1 = (const float*)d_in[16];
  const float* b1 = (const float*)d_in[17];
  const float* W2 = (const float*)d_in[18];
  const float* b2 = (const float*)d_in[19];
  const float* W3 = (const float*)d_in[20];
  const float* b3 = (const float*)d_in[21];
  float* out = (float*)d_out;

  const int E = NEDGES;
  char* ws = (char*)d_ws;
  size_t o = 0;
  auto alloc = [&](size_t bytes) { void* p = ws + o; o = (o + bytes + 255) & ~(size_t)255; return p; };
  _Float16* XH = (_Float16*)alloc((size_t)NNODES * 128 * 2);
  _Float16* MEANH = (_Float16*)alloc((size_t)NNODES * 128 * 2);
  int* ESORT = (int*)alloc((size_t)E * 4);
  int* ESORTL = (int*)alloc((size_t)E * 4);
  int* PART = (int*)alloc((size_t)GRAPHS * NSB * 2048 * 4);
  int* CURS = (int*)alloc((size_t)GRAPHS * NSB * 2048 * 4);
  int* OFFB = (int*)alloc((size_t)NNODES * 4);
  int* DEG = (int*)alloc((size_t)NNODES * 4);
  float* SC = (float*)alloc((size_t)NNODES * 4);
  int* NOOA = (int*)alloc((size_t)NNODES * 4);
  int* RANKT = (int*)alloc((size_t)NNODES * 4);
  int* ORIGA = (int*)alloc((size_t)NNODES * 4);
  int* ORIGB = (int*)alloc((size_t)NNODES * 4);
  _Float16* WH0 = (_Float16*)alloc(4096 * 8 * 2);
  _Float16* WH1 = (_Float16*)alloc(4096 * 8 * 2);
  _Float16* WH2 = (_Float16*)alloc(4096 * 8 * 2);
  float* PMAX = (float*)alloc((size_t)GRAPHS * RSL * 128 * 4);
  float* PSUM = (float*)alloc((size_t)GRAPHS * RSL * 128 * 4);
  float* H = (float*)alloc(64 * 256 * 4);
  float* H1 = (float*)alloc(64 * 128 * 4);
  float* H2 = (float*)alloc(64 * 64 * 4);

  embed_kernel<<<NNODES * 16 / 256, 256, 0, stream>>>(node_ids, emb, XH);
  hipMemsetAsync(H, 0, 64 * 256 * 4, stream);
  convert_w<<<16, 256, 0, stream>>>(W[0][0], W[0][1], WH0);
  convert_w<<<16, 256, 0, stream>>>(W[1][0], W[1][1], WH1);
  convert_w<<<16, 256, 0, stream>>>(W[2][0], W[2][1], WH2);

  // layer-0 CSR (built once; layers 1/2 use remapped edge values)
  const int* src = ei;
  const int* dst = ei + E;
  csr_hist<<<GRAPHS * NSB, 1024, 0, stream>>>(src, dst, NPG, PART);
  csr_scan<<<GRAPHS, 1024, 0, stream>>>(PART, NPG, OFFB, DEG, CURS);
  csr_place<<<GRAPHS * NSB, 1024, 0, stream>>>(src, dst, NPG, CURS, ESORT);

  struct LayerP { int n, k; };                 // n = current node count; k = keep per graph
  LayerP L[3] = {{131072, 1639}, {104896, 1312}, {83968, 1050}};
  _Float16* WHs[3] = {WH0, WH1, WH2};
  int* ORIG_cur = ORIGA;   // maps current ids -> original ids (valid for li>=1)
  int* ORIG_next = ORIGB;

  for (int li = 0; li < 3; ++li) {
    int n = L[li].n, k = L[li].k;
    int np = n / 64;
    const float *bl = W[li][2], *pw = W[li][3];

    int C = (np + 15) / 16;
    if (li == 0) {
      aggregate_kernel<<<64 * C, 256, 0, stream>>>(XH, OFFB, DEG, ESORT, MEANH, np, C);
    } else {
      remap_esort<<<E / 4 / 256, 256, 0, stream>>>(ESORT, NOOA, ESORTL, E / 4);
      aggregate_f<<<64 * C, 256, 0, stream>>>(XH, OFFB, DEG, ESORTL, ORIG_cur,
                                              MEANH, np, C);
    }
    sage_gemm<<<(n + RPB - 1) / RPB, 256, 0, stream>>>(XH, MEANH, MEANH, WHs[li], bl, pw, SC, n);
    topk_sort<<<GRAPHS, 1024, 0, stream>>>(SC, np, k, NOOA, RANKT, li);
    topk_tail<<<GRAPHS * RSL, 256, 0, stream>>>(SC, RANKT, np, k, MEANH, XH,
        (li == 0) ? nullptr : ORIG_cur, ORIG_next, PMAX, PSUM);
    readout_comb<<<32, 256, 0, stream>>>(PMAX, PSUM, k, H);
    { int* t = ORIG_cur; ORIG_cur = ORIG_next; ORIG_next = t; }
  }

  mlp1<<<32, 256, 0, stream>>>(H, W1, b1, H1);
  mlp2<<<16, 256, 0, stream>>>(H1, W2, b2, H2);
  mlp3<<<1, 64, 0, stream>>>(H2, W3, b3, out);
}

// Round 17
// 331.622 us; speedup vs baseline: 1.6994x; 1.0959x over previous
//
#include <hip/hip_runtime.h>
#include <hip/hip_bf16.h>
#include <float.h>

typedef _Float16 f16x8 __attribute__((ext_vector_type(8)));
typedef float f32x4 __attribute__((ext_vector_type(4)));

#define GRAPHS 64
#define NPG 2048
#define DIM 128
#define NNODES (GRAPHS * NPG)
#define NEDGES (NNODES * 16)
#define ECAP 32768   // edges per graph
#define NSB 8        // sub-blocks per graph for CSR build
#define RSL 16       // readout slices per graph
#define RPB 256      // rows per block in sage_gemm

// ---------------- embed: xh[i] = (f16) emb[node_ids[i]] ----------------
__global__ __launch_bounds__(256) void embed_kernel(const int* __restrict__ ids,
    const float* __restrict__ emb, _Float16* __restrict__ xh) {
  int idx = blockIdx.x * 256 + threadIdx.x;
  int nd = idx >> 4, part = idx & 15;
  int id = ids[nd];
  const float* src = emb + (size_t)id * 128 + part * 8;
  float4 a = *(const float4*)(src);
  float4 b = *(const float4*)(src + 4);
  f16x8 o;
  o[0] = (_Float16)a.x; o[1] = (_Float16)a.y; o[2] = (_Float16)a.z; o[3] = (_Float16)a.w;
  o[4] = (_Float16)b.x; o[5] = (_Float16)b.y; o[6] = (_Float16)b.z; o[7] = (_Float16)b.w;
  *(f16x8*)(xh + (size_t)nd * 128 + part * 8) = o;
}

// ---------------- pre-convert weights (3 layers in one launch) ---------------
__global__ __launch_bounds__(256) void convert_w3(const float* __restrict__ Wl0,
    const float* __restrict__ Wr0, const float* __restrict__ Wl1, const float* __restrict__ Wr1,
    const float* __restrict__ Wl2, const float* __restrict__ Wr2,
    _Float16* __restrict__ wh0, _Float16* __restrict__ wh1, _Float16* __restrict__ wh2) {
  int li = blockIdx.x >> 4;
  int qq = (blockIdx.x & 15) * 256 + threadIdx.x;   // 0..4095
  const float* Wl = (li == 0) ? Wl0 : ((li == 1) ? Wl1 : Wl2);
  const float* Wr = (li == 0) ? Wr0 : ((li == 1) ? Wr1 : Wr2);
  _Float16* wh = (li == 0) ? wh0 : ((li == 1) ? wh1 : wh2);
  int ks = qq >> 9, nf = (qq >> 6) & 7, l = qq & 63;
  int ncol = nf * 16 + (l & 15);
  int k0 = (ks & 3) * 32 + ((l >> 4) << 3);
  const float* wsrc = ((ks < 4) ? Wl : Wr) + ncol * 128 + k0;
  float4 a = *(const float4*)wsrc;
  float4 b = *(const float4*)(wsrc + 4);
  f16x8 w;
  w[0] = (_Float16)a.x; w[1] = (_Float16)a.y; w[2] = (_Float16)a.z; w[3] = (_Float16)a.w;
  w[4] = (_Float16)b.x; w[5] = (_Float16)b.y; w[6] = (_Float16)b.z; w[7] = (_Float16)b.w;
  *(f16x8*)(wh + (size_t)qq * 8) = w;
}

// ---------------- CSR build (layer 0 only), 3 phases ------------------------
__global__ __launch_bounds__(1024) void csr_hist(const int* __restrict__ src,
    const int* __restrict__ dst, int np, int* __restrict__ part) {
  __shared__ int hist[2048];
  int x = blockIdx.x;
  int s = x & 7, q = x >> 3;
  int b = q & (NSB - 1), gh = q >> 3;
  int g = gh * 8 + s;
  int tid = threadIdx.x;
  for (int i = tid; i < 2048; i += 1024) hist[i] = 0;
  __syncthreads();
  int e0 = g * ECAP + b * (ECAP / NSB);
  int nodebase = g * np;
  for (int e = tid; e < ECAP / NSB; e += 1024) {
    atomicAdd(&hist[dst[e0 + e] - nodebase], 1);
  }
  __syncthreads();
  for (int i = tid; i < np; i += 1024) part[((size_t)(g * NSB + b)) * 2048 + i] = hist[i];
}

__global__ __launch_bounds__(1024) void csr_scan(const int* __restrict__ part, int np,
    int* __restrict__ offb, int* __restrict__ deg, int* __restrict__ curs) {
  __shared__ int psum[1024];
  int g = blockIdx.x, tid = threadIdx.x;
  int i0 = 2 * tid, i1 = 2 * tid + 1;
  int p0[NSB], p1[NSB];
  int c0 = 0, c1 = 0;
#pragma unroll
  for (int b = 0; b < NSB; ++b) {
    p0[b] = (i0 < np) ? part[((size_t)(g * NSB + b)) * 2048 + i0] : 0;
    p1[b] = (i1 < np) ? part[((size_t)(g * NSB + b)) * 2048 + i1] : 0;
    c0 += p0[b]; c1 += p1[b];
  }
  int pair = c0 + c1;
  psum[tid] = pair;
  for (int s = 1; s < 1024; s <<= 1) {
    __syncthreads();
    int t = (tid >= s) ? psum[tid - s] : 0;
    __syncthreads();
    psum[tid] += t;
  }
  int excl = psum[tid] - pair;
  int ebase = g * ECAP;
  int nodebase = g * np;
  if (i0 < np) {
    int off = ebase + excl;
    offb[nodebase + i0] = off;
    deg[nodebase + i0] = c0;
    int cur = off;
#pragma unroll
    for (int b = 0; b < NSB; ++b) { curs[((size_t)(g * NSB + b)) * 2048 + i0] = cur; cur += p0[b]; }
  }
  if (i1 < np) {
    int off = ebase + excl + c0;
    offb[nodebase + i1] = off;
    deg[nodebase + i1] = c1;
    int cur = off;
#pragma unroll
    for (int b = 0; b < NSB; ++b) { curs[((size_t)(g * NSB + b)) * 2048 + i1] = cur; cur += p1[b]; }
  }
}

__global__ __launch_bounds__(1024) void csr_place(const int* __restrict__ src,
    const int* __restrict__ dst, int np, const int* __restrict__ curs,
    int* __restrict__ esort) {
  __shared__ int cur[2048];
  int x = blockIdx.x;
  int s = x & 7, q = x >> 3;
  int b = q & (NSB - 1), gh = q >> 3;
  int g = gh * 8 + s;
  int tid = threadIdx.x;
  for (int i = tid; i < np; i += 1024) cur[i] = curs[((size_t)(g * NSB + b)) * 2048 + i];
  __syncthreads();
  int e0 = g * ECAP + b * (ECAP / NSB);
  int nodebase = g * np;
  for (int e = tid; e < ECAP / NSB; e += 1024) {
    int ge = e0 + e;
    int p = atomicAdd(&cur[dst[ge] - nodebase], 1);
    esort[p] = src[ge];
  }
}

// ---------------- remap edge list through pool map (streaming, 4/thread) -----
__global__ __launch_bounds__(256) void remap_esort(const int* __restrict__ esort0,
    const int* __restrict__ noo, int* __restrict__ esortl, int E4) {
  int t = blockIdx.x * 256 + threadIdx.x;
  if (t >= E4) return;
  int4 s = *(const int4*)(esort0 + t * 4);
  int4 o;
  o.x = noo[s.x]; o.y = noo[s.y]; o.z = noo[s.z]; o.w = noo[s.w];
  *(int4*)(esortl + t * 4) = o;
}

// ---------------- aggregate (layer 0): mean over incoming edges --------------
__global__ __launch_bounds__(256) void aggregate_kernel(const _Float16* __restrict__ xh,
    const int* __restrict__ offb, const int* __restrict__ deg, const int* __restrict__ esrc,
    _Float16* __restrict__ meanh, int np, int C) {
  int bid = blockIdx.x;
  int s = bid & 7, q = bid >> 3;
  int gsub = q / C, chunk = q - gsub * C;
  int g = gsub * 8 + s;
  int wave = threadIdx.x >> 6, lane = threadIdx.x & 63;
  int sub = lane >> 4, l = lane & 15;
  int local = chunk * 16 + wave * 4 + sub;
  if (local >= np) return;
  int w = g * np + local;
  int b = offb[w], c = deg[w];
  int e = b + c;
  float acc[8] = {0.f, 0.f, 0.f, 0.f, 0.f, 0.f, 0.f, 0.f};
  int i = b;
  for (; i + 4 <= e; i += 4) {
    int s0 = esrc[i], s1 = esrc[i + 1], s2 = esrc[i + 2], s3 = esrc[i + 3];
    f16x8 v0 = *(const f16x8*)(xh + (size_t)s0 * 128 + l * 8);
    f16x8 v1 = *(const f16x8*)(xh + (size_t)s1 * 128 + l * 8);
    f16x8 v2 = *(const f16x8*)(xh + (size_t)s2 * 128 + l * 8);
    f16x8 v3 = *(const f16x8*)(xh + (size_t)s3 * 128 + l * 8);
    f16x8 t = (v0 + v1) + (v2 + v3);
#pragma unroll
    for (int j = 0; j < 8; ++j) acc[j] += (float)t[j];
  }
  for (; i < e; ++i) {
    int srcn = esrc[i];
    f16x8 v = *(const f16x8*)(xh + (size_t)srcn * 128 + l * 8);
#pragma unroll
    for (int j = 0; j < 8; ++j) acc[j] += (float)v[j];
  }
  float inv = 1.f / (float)(c > 0 ? c : 1);
  f16x8 o;
#pragma unroll
  for (int j = 0; j < 8; ++j) o[j] = (_Float16)(acc[j] * inv);
  *(f16x8*)(meanh + (size_t)w * 128 + l * 8) = o;
}

// ---------------- aggregate (layers 1/2): pre-mapped edge list, -1 = dropped --
__global__ __launch_bounds__(256) void aggregate_f(const _Float16* __restrict__ xh,
    const int* __restrict__ offb0, const int* __restrict__ deg0, const int* __restrict__ esortl,
    const int* __restrict__ orig, _Float16* __restrict__ meanh, int np, int C) {
  int bid = blockIdx.x;
  int s = bid & 7, q = bid >> 3;
  int gsub = q / C, chunk = q - gsub * C;
  int g = gsub * 8 + s;
  int wave = threadIdx.x >> 6, lane = threadIdx.x & 63;
  int sub = lane >> 4, l = lane & 15;
  int local = chunk * 16 + wave * 4 + sub;
  if (local >= np) return;
  int w = g * np + local;
  int o = orig[w];
  int b = offb0[o], c0 = deg0[o];
  int e = b + c0;
  float acc[8] = {0.f, 0.f, 0.f, 0.f, 0.f, 0.f, 0.f, 0.f};
  int cnt = 0;
  const f16x8 zero = {(_Float16)0.f, (_Float16)0.f, (_Float16)0.f, (_Float16)0.f,
                      (_Float16)0.f, (_Float16)0.f, (_Float16)0.f, (_Float16)0.f};
  int i = b;
  for (; i + 4 <= e; i += 4) {
    int n0 = esortl[i], n1 = esortl[i + 1], n2 = esortl[i + 2], n3 = esortl[i + 3];
    f16x8 v0 = zero, v1 = zero, v2 = zero, v3 = zero;
    if (n0 >= 0) v0 = *(const f16x8*)(xh + (size_t)n0 * 128 + l * 8);
    if (n1 >= 0) v1 = *(const f16x8*)(xh + (size_t)n1 * 128 + l * 8);
    if (n2 >= 0) v2 = *(const f16x8*)(xh + (size_t)n2 * 128 + l * 8);
    if (n3 >= 0) v3 = *(const f16x8*)(xh + (size_t)n3 * 128 + l * 8);
    cnt += (n0 >= 0) + (n1 >= 0) + (n2 >= 0) + (n3 >= 0);
    f16x8 t = (v0 + v1) + (v2 + v3);
#pragma unroll
    for (int j = 0; j < 8; ++j) acc[j] += (float)t[j];
  }
  for (; i < e; ++i) {
    int sn = esortl[i];
    if (sn < 0) continue;
    ++cnt;
    f16x8 v = *(const f16x8*)(xh + (size_t)sn * 128 + l * 8);
#pragma unroll
    for (int j = 0; j < 8; ++j) acc[j] += (float)v[j];
  }
  float inv = 1.f / (float)(cnt > 0 ? cnt : 1);
  f16x8 ov;
#pragma unroll
  for (int j = 0; j < 8; ++j) ov[j] = (_Float16)(acc[j] * inv);
  *(f16x8*)(meanh + (size_t)w * 128 + l * 8) = ov;
}

// ---------------- fused SAGE transform + score (LDS weight stage) -------------
__global__ __launch_bounds__(256, 2) void sage_gemm(const _Float16* __restrict__ XH,
    const _Float16* MEANIN, _Float16* OUT, const _Float16* __restrict__ WH,
    const float* __restrict__ bl, const float* __restrict__ pw, float* __restrict__ sc,
    int n) {
  __shared__ _Float16 WB[4096 * 8];  // 64KB, layout [ks][nf][lane][8]
  int tid = threadIdx.x;
  for (int qq = tid; qq < 4096; qq += 256)
    *(f16x8*)(WB + qq * 8) = *(const f16x8*)(WH + (size_t)qq * 8);
  __syncthreads();
  int wave = tid >> 6, lane = tid & 63;
  int wrow0 = blockIdx.x * RPB + wave * 64;
  if (wrow0 >= n) return;
  int kb = (lane >> 4) << 3;
  int lr = lane & 15;
  f32x4 acc[4][8];
#pragma unroll
  for (int t = 0; t < 4; ++t)
#pragma unroll
    for (int nf = 0; nf < 8; ++nf) acc[t][nf] = (f32x4){0.f, 0.f, 0.f, 0.f};
#pragma unroll
  for (int ks = 0; ks < 8; ++ks) {
    const _Float16* A = (ks < 4) ? MEANIN : XH;
    const _Float16* ap = A + (size_t)(wrow0 + lr) * 128 + (ks & 3) * 32 + kb;
    f16x8 a0 = *(const f16x8*)(ap);
    f16x8 a1 = *(const f16x8*)(ap + 16 * 128);
    f16x8 a2 = *(const f16x8*)(ap + 32 * 128);
    f16x8 a3 = *(const f16x8*)(ap + 48 * 128);
#pragma unroll
    for (int nf = 0; nf < 8; ++nf) {
      f16x8 b = *(const f16x8*)(WB + ((ks * 8 + nf) * 64 + lane) * 8);
      acc[0][nf] = __builtin_amdgcn_mfma_f32_16x16x32_f16(a0, b, acc[0][nf], 0, 0, 0);
      acc[1][nf] = __builtin_amdgcn_mfma_f32_16x16x32_f16(a1, b, acc[1][nf], 0, 0, 0);
      acc[2][nf] = __builtin_amdgcn_mfma_f32_16x16x32_f16(a2, b, acc[2][nf], 0, 0, 0);
      acc[3][nf] = __builtin_amdgcn_mfma_f32_16x16x32_f16(a3, b, acc[3][nf], 0, 0, 0);
    }
  }
  float pwv[8], qn = 0.f;
#pragma unroll
  for (int nf = 0; nf < 8; ++nf) {
    pwv[nf] = pw[nf * 16 + lr];
    qn += pwv[nf] * pwv[nf];
  }
#pragma unroll
  for (int o = 1; o < 16; o <<= 1) qn += __shfl_xor(qn, o);
  float inv_n = 1.f / sqrtf(qn);
#pragma unroll
  for (int t = 0; t < 4; ++t) {
    int rbase = wrow0 + t * 16 + ((lane >> 4) << 2);
    float dot[4] = {0.f, 0.f, 0.f, 0.f};
#pragma unroll
    for (int nf = 0; nf < 8; ++nf) {
      int col = nf * 16 + lr;
      float bias = bl[col];
#pragma unroll
      for (int r = 0; r < 4; ++r) {
        float v = fmaxf(acc[t][nf][r] + bias, 0.f);
        OUT[(size_t)(rbase + r) * 128 + col] = (_Float16)v;
        dot[r] += v * pwv[nf];
      }
    }
#pragma unroll
    for (int r = 0; r < 4; ++r) {
#pragma unroll
      for (int o = 1; o < 16; o <<= 1) dot[r] += __shfl_xor(dot[r], o);
    }
    if (lr == 0) {
#pragma unroll
      for (int r = 0; r < 4; ++r) sc[rbase + r] = tanhf(dot[r] * inv_n);
    }
  }
}

// ---------------- top-k sort: bitonic + NOO map + rank table -----------------
// one block per graph. mode: 0 = write nooA, 1 = compose nooA, 2 = skip.
__global__ __launch_bounds__(1024) void topk_sort(const float* __restrict__ sc,
    int n_per, int k, int* __restrict__ nooA, int* __restrict__ rankt, int mode) {
  __shared__ unsigned long long L[2048];
  __shared__ int c2n[2048];
  int g = blockIdx.x;
  int tid = threadIdx.x;
  int lane = tid & 63, wave = tid >> 6;
  int i0 = wave * 128 + lane;
  int i1 = i0 + 64;
  const float* scg = sc + g * n_per;
  auto keyize = [&](int i) -> unsigned long long {
    float f = (i < n_per) ? scg[i] : -FLT_MAX;
    unsigned u = __float_as_uint(f);
    u = (u & 0x80000000u) ? ~u : (u | 0x80000000u);  // monotone float->uint map
    return ((unsigned long long)u << 32) | (unsigned)(2047 - i);
  };
  unsigned long long a = keyize(i0), b = keyize(i1);
#pragma clang loop unroll(disable)
  for (unsigned kk = 2; kk <= 2048; kk <<= 1) {
#pragma clang loop unroll(disable)
    for (unsigned j = kk >> 1; j >= 128; j >>= 1) {
      L[i0] = a; L[i1] = b;
      __syncthreads();
      unsigned long long pa = L[i0 ^ j], pb = L[i1 ^ j];
      bool dA = ((i0 & kk) == 0), lA = ((i0 & j) == 0);
      if ((dA == lA) ? (pa > a) : (pa < a)) a = pa;
      bool dB = ((i1 & kk) == 0), lB = ((i1 & j) == 0);
      if ((dB == lB) ? (pb > b) : (pb < b)) b = pb;
      __syncthreads();
    }
    if (kk >= 128) {
      bool desc = ((i0 & kk) == 0);
      if ((a < b) == desc) { unsigned long long t = a; a = b; b = t; }
    }
    unsigned jtop = (kk >> 1 < 32u) ? (kk >> 1) : 32u;
#pragma clang loop unroll(disable)
    for (unsigned j = jtop; j >= 1; j >>= 1) {
      unsigned long long oa = __shfl_xor(a, (int)j);
      unsigned long long ob = __shfl_xor(b, (int)j);
      bool low = ((lane & j) == 0);
      bool dA = ((i0 & kk) == 0);
      if ((dA == low) ? (oa > a) : (oa < a)) a = oa;
      bool dB = ((i1 & kk) == 0);
      if ((dB == low) ? (ob > b) : (ob < b)) b = ob;
    }
  }
  int orig_a = 2047 - (int)(a & 0xFFFFFFFFu);
  int orig_b = 2047 - (int)(b & 0xFFFFFFFFu);
  if (i0 < k) rankt[g * NPG + i0] = orig_a;
  if (i1 < k) rankt[g * NPG + i1] = orig_b;
  if (mode == 0) {
    if (orig_a < n_per) nooA[g * n_per + orig_a] = (i0 < k) ? g * k + i0 : -1;
    if (orig_b < n_per) nooA[g * n_per + orig_b] = (i1 < k) ? g * k + i1 : -1;
  } else if (mode == 1) {
    if (orig_a < n_per) c2n[orig_a] = (i0 < k) ? g * k + i0 : -1;
    if (orig_b < n_per) c2n[orig_b] = (i1 < k) ? g * k + i1 : -1;
    __syncthreads();
    for (int o2 = tid; o2 < NPG; o2 += 1024) {
      int a0 = nooA[g * NPG + o2];
      nooA[g * NPG + o2] = (a0 >= 0) ? c2n[a0 - g * n_per] : -1;
    }
  }
}

// ---------------- top-k tail: gather+scale+XH write+ORIG+readout partials -----
// grid = GRAPHS * RSL blocks, 256 threads; block handles rows [r0, r1) of k.
// pmax/psum are per-layer slices (caller offsets).
__global__ __launch_bounds__(256) void topk_tail(const float* __restrict__ sc,
    const int* __restrict__ rankt, int n_per, int k, const _Float16* __restrict__ meanin,
    _Float16* __restrict__ xh, const int* __restrict__ orig_in, int* __restrict__ orig_out,
    float* __restrict__ pmax, float* __restrict__ psum) {
  int g = blockIdx.x >> 4;
  int slice = blockIdx.x & (RSL - 1);
  int rpb = (k + RSL - 1) / RSL;
  int r0 = slice * rpb;
  int r1 = r0 + rpb; if (r1 > k) r1 = k;
  const float* scg = sc + g * n_per;
  int grp = threadIdx.x >> 4, l8 = threadIdx.x & 15;
  float vmax[8], vsum[8];
#pragma unroll
  for (int j = 0; j < 8; ++j) { vmax[j] = -FLT_MAX; vsum[j] = 0.f; }
  for (int r = r0 + grp; r < r1; r += 16) {
    int orig = rankt[g * NPG + r];
    int p = g * n_per + orig;
    float score = scg[orig];
    f16x8 v = *(const f16x8*)(meanin + (size_t)p * 128 + l8 * 8);
    f16x8 ovv;
#pragma unroll
    for (int j = 0; j < 8; ++j) {
      float val = (float)v[j] * score;
      ovv[j] = (_Float16)val;
      vmax[j] = fmaxf(vmax[j], val);
      vsum[j] += val;
    }
    *(f16x8*)(xh + (size_t)(g * k + r) * 128 + l8 * 8) = ovv;
    if (l8 == 0) orig_out[g * k + r] = orig_in ? orig_in[p] : p;
  }
  // reduce 16 groups: lane-xor within wave (16,32), then LDS across 4 waves
  __shared__ float smax[4 * 128], ssum[4 * 128];
  int lane = threadIdx.x & 63, wave = threadIdx.x >> 6;
#pragma unroll
  for (int j = 0; j < 8; ++j) {
    vmax[j] = fmaxf(vmax[j], __shfl_xor(vmax[j], 16));
    vmax[j] = fmaxf(vmax[j], __shfl_xor(vmax[j], 32));
    vsum[j] += __shfl_xor(vsum[j], 16);
    vsum[j] += __shfl_xor(vsum[j], 32);
  }
  if ((lane >> 4) == 0) {
#pragma unroll
    for (int j = 0; j < 8; ++j) {
      smax[wave * 128 + l8 * 8 + j] = vmax[j];
      ssum[wave * 128 + l8 * 8 + j] = vsum[j];
    }
  }
  __syncthreads();
  if (threadIdx.x < 128) {
    int d = threadIdx.x;
    float m = fmaxf(fmaxf(smax[d], smax[128 + d]), fmaxf(smax[256 + d], smax[384 + d]));
    float s2 = ssum[d] + ssum[128 + d] + ssum[256 + d] + ssum[384 + d];
    pmax[(size_t)(g * RSL + slice) * 128 + d] = m;
    psum[(size_t)(g * RSL + slice) * 128 + d] = s2;
  }
}

// ---------------- fused readout-combine (3 layers) + MLP ----------------------
// one block per graph, 256 threads.
__global__ __launch_bounds__(256) void mlp_fused(const float* __restrict__ pmax,
    const float* __restrict__ psum, int k0, int k1, int k2,
    const float* __restrict__ W1, const float* __restrict__ b1,
    const float* __restrict__ W2, const float* __restrict__ b2,
    const float* __restrict__ W3, const float* __restrict__ b3, float* __restrict__ out) {
  __shared__ float h[256], h1[128], h2[64];
  int g = blockIdx.x, t = threadIdx.x;
  int ks[3] = {k0, k1, k2};
  if (t < 128) {
    float hm = 0.f, hs = 0.f;
#pragma unroll
    for (int li = 0; li < 3; ++li) {
      const float* pm = pmax + ((size_t)li * GRAPHS + g) * RSL * 128;
      const float* ps = psum + ((size_t)li * GRAPHS + g) * RSL * 128;
      float m = -FLT_MAX, s = 0.f;
#pragma unroll
      for (int sl = 0; sl < RSL; ++sl) {
        m = fmaxf(m, pm[sl * 128 + t]);
        s += ps[sl * 128 + t];
      }
      hm += m;
      hs += s / (float)ks[li];
    }
    h[t] = hm;
    h[128 + t] = hs;
  }
  __syncthreads();
  if (t < 128) {
    const float* wp = W1 + t * 256;
    float a = b1[t];
    for (int c = 0; c < 256; ++c) a += h[c] * wp[c];
    h1[t] = fmaxf(a, 0.f);
  }
  __syncthreads();
  if (t < 64) {
    const float* wp = W2 + t * 128;
    float a = b2[t];
    for (int c = 0; c < 128; ++c) a += h1[c] * wp[c];
    h2[t] = fmaxf(a, 0.f);
  }
  __syncthreads();
  if (t < 64) {
    float a = h2[t] * W3[t];
#pragma unroll
    for (int o = 32; o >= 1; o >>= 1) a += __shfl_xor(a, o);
    if (t == 0) out[g] = 1.f / (1.f + expf(-(a + b3[0])));
  }
}

extern "C" void kernel_launch(void* const* d_in, const int* in_sizes, int n_in,
                              void* d_out, int out_size, void* d_ws, size_t ws_size,
                              hipStream_t stream) {
  const int* node_ids = (const int*)d_in[0];
  const int* ei = (const int*)d_in[1];
  const float* emb = (const float*)d_in[3];
  const float* W[3][4] = {
      {(const float*)d_in[4], (const float*)d_in[5], (const float*)d_in[6], (const float*)d_in[7]},
      {(const float*)d_in[8], (const float*)d_in[9], (const float*)d_in[10], (const float*)d_in[11]},
      {(const float*)d_in[12], (const float*)d_in[13], (const float*)d_in[14], (const float*)d_in[15]}};
  const float* W1 = (const float*)d_in[16];
  const float* b1 = (const float*)d_in[17];
  const float* W2 = (const float*)d_in[18];
  const float* b2 = (const float*)d_in[19];
  const float* W3 = (const float*)d_in[20];
  const float* b3 = (const float*)d_in[21];
  float* out = (float*)d_out;

  const int E = NEDGES;
  char* ws = (char*)d_ws;
  size_t o = 0;
  auto alloc = [&](size_t bytes) { void* p = ws + o; o = (o + bytes + 255) & ~(size_t)255; return p; };
  _Float16* XH = (_Float16*)alloc((size_t)NNODES * 128 * 2);
  _Float16* MEANH = (_Float16*)alloc((size_t)NNODES * 128 * 2);
  int* ESORT = (int*)alloc((size_t)E * 4);
  int* ESORTL = (int*)alloc((size_t)E * 4);
  int* PART = (int*)alloc((size_t)GRAPHS * NSB * 2048 * 4);
  int* CURS = (int*)alloc((size_t)GRAPHS * NSB * 2048 * 4);
  int* OFFB = (int*)alloc((size_t)NNODES * 4);
  int* DEG = (int*)alloc((size_t)NNODES * 4);
  float* SC = (float*)alloc((size_t)NNODES * 4);
  int* NOOA = (int*)alloc((size_t)NNODES * 4);
  int* RANKT = (int*)alloc((size_t)NNODES * 4);
  int* ORIGA = (int*)alloc((size_t)NNODES * 4);
  int* ORIGB = (int*)alloc((size_t)NNODES * 4);
  _Float16* WH0 = (_Float16*)alloc(4096 * 8 * 2);
  _Float16* WH1 = (_Float16*)alloc(4096 * 8 * 2);
  _Float16* WH2 = (_Float16*)alloc(4096 * 8 * 2);
  float* PMAX = (float*)alloc((size_t)3 * GRAPHS * RSL * 128 * 4);
  float* PSUM = (float*)alloc((size_t)3 * GRAPHS * RSL * 128 * 4);

  embed_kernel<<<NNODES * 16 / 256, 256, 0, stream>>>(node_ids, emb, XH);
  convert_w3<<<48, 256, 0, stream>>>(W[0][0], W[0][1], W[1][0], W[1][1], W[2][0], W[2][1],
                                     WH0, WH1, WH2);

  // layer-0 CSR (built once; layers 1/2 use remapped edge values)
  const int* src = ei;
  const int* dst = ei + E;
  csr_hist<<<GRAPHS * NSB, 1024, 0, stream>>>(src, dst, NPG, PART);
  csr_scan<<<GRAPHS, 1024, 0, stream>>>(PART, NPG, OFFB, DEG, CURS);
  csr_place<<<GRAPHS * NSB, 1024, 0, stream>>>(src, dst, NPG, CURS, ESORT);

  struct LayerP { int n, k; };                 // n = current node count; k = keep per graph
  LayerP L[3] = {{131072, 1639}, {104896, 1312}, {83968, 1050}};
  _Float16* WHs[3] = {WH0, WH1, WH2};
  int* ORIG_cur = ORIGA;   // maps current ids -> original ids (valid for li>=1)
  int* ORIG_next = ORIGB;

  for (int li = 0; li < 3; ++li) {
    int n = L[li].n, k = L[li].k;
    int np = n / 64;
    const float *bl = W[li][2], *pw = W[li][3];

    int C = (np + 15) / 16;
    if (li == 0) {
      aggregate_kernel<<<64 * C, 256, 0, stream>>>(XH, OFFB, DEG, ESORT, MEANH, np, C);
    } else {
      remap_esort<<<E / 4 / 256, 256, 0, stream>>>(ESORT, NOOA, ESORTL, E / 4);
      aggregate_f<<<64 * C, 256, 0, stream>>>(XH, OFFB, DEG, ESORTL, ORIG_cur,
                                              MEANH, np, C);
    }
    sage_gemm<<<(n + RPB - 1) / RPB, 256, 0, stream>>>(XH, MEANH, MEANH, WHs[li], bl, pw, SC, n);
    topk_sort<<<GRAPHS, 1024, 0, stream>>>(SC, np, k, NOOA, RANKT, li);
    topk_tail<<<GRAPHS * RSL, 256, 0, stream>>>(SC, RANKT, np, k, MEANH, XH,
        (li == 0) ? nullptr : ORIG_cur, ORIG_next,
        PMAX + (size_t)li * GRAPHS * RSL * 128, PSUM + (size_t)li * GRAPHS * RSL * 128);
    { int* t = ORIG_cur; ORIG_cur = ORIG_next; ORIG_next = t; }
  }

  mlp_fused<<<GRAPHS, 256, 0, stream>>>(PMAX, PSUM, L[0].k, L[1].k, L[2].k,
                                        W1, b1, W2, b2, W3, b3, out);
}

// Round 18
// 317.563 us; speedup vs baseline: 1.7746x; 1.0443x over previous
//
#include <hip/hip_runtime.h>
#include <hip/hip_bf16.h>
#include <float.h>

typedef _Float16 f16x8 __attribute__((ext_vector_type(8)));
typedef float f32x4 __attribute__((ext_vector_type(4)));

#define GRAPHS 64
#define NPG 2048
#define DIM 128
#define NNODES (GRAPHS * NPG)
#define NEDGES (NNODES * 16)
#define ECAP 32768   // edges per graph
#define NSB 8        // sub-blocks per graph for CSR build
#define RSL 16       // readout slices per graph
#define RPB 512      // rows per block in sage_gemm (8 waves x 64 rows)

// ---------------- embed: xh[i] = (f16) emb[node_ids[i]] ----------------
__global__ __launch_bounds__(256) void embed_kernel(const int* __restrict__ ids,
    const float* __restrict__ emb, _Float16* __restrict__ xh) {
  int idx = blockIdx.x * 256 + threadIdx.x;
  int nd = idx >> 4, part = idx & 15;
  int id = ids[nd];
  const float* src = emb + (size_t)id * 128 + part * 8;
  float4 a = *(const float4*)(src);
  float4 b = *(const float4*)(src + 4);
  f16x8 o;
  o[0] = (_Float16)a.x; o[1] = (_Float16)a.y; o[2] = (_Float16)a.z; o[3] = (_Float16)a.w;
  o[4] = (_Float16)b.x; o[5] = (_Float16)b.y; o[6] = (_Float16)b.z; o[7] = (_Float16)b.w;
  *(f16x8*)(xh + (size_t)nd * 128 + part * 8) = o;
}

// ---------------- pre-convert weights (3 layers in one launch) ---------------
__global__ __launch_bounds__(256) void convert_w3(const float* __restrict__ Wl0,
    const float* __restrict__ Wr0, const float* __restrict__ Wl1, const float* __restrict__ Wr1,
    const float* __restrict__ Wl2, const float* __restrict__ Wr2,
    _Float16* __restrict__ wh0, _Float16* __restrict__ wh1, _Float16* __restrict__ wh2) {
  int li = blockIdx.x >> 4;
  int qq = (blockIdx.x & 15) * 256 + threadIdx.x;   // 0..4095
  const float* Wl = (li == 0) ? Wl0 : ((li == 1) ? Wl1 : Wl2);
  const float* Wr = (li == 0) ? Wr0 : ((li == 1) ? Wr1 : Wr2);
  _Float16* wh = (li == 0) ? wh0 : ((li == 1) ? wh1 : wh2);
  int ks = qq >> 9, nf = (qq >> 6) & 7, l = qq & 63;
  int ncol = nf * 16 + (l & 15);
  int k0 = (ks & 3) * 32 + ((l >> 4) << 3);
  const float* wsrc = ((ks < 4) ? Wl : Wr) + ncol * 128 + k0;
  float4 a = *(const float4*)wsrc;
  float4 b = *(const float4*)(wsrc + 4);
  f16x8 w;
  w[0] = (_Float16)a.x; w[1] = (_Float16)a.y; w[2] = (_Float16)a.z; w[3] = (_Float16)a.w;
  w[4] = (_Float16)b.x; w[5] = (_Float16)b.y; w[6] = (_Float16)b.z; w[7] = (_Float16)b.w;
  *(f16x8*)(wh + (size_t)qq * 8) = w;
}

// ---------------- CSR build (layer 0 only), 3 phases ------------------------
__global__ __launch_bounds__(1024) void csr_hist(const int* __restrict__ src,
    const int* __restrict__ dst, int np, int* __restrict__ part) {
  __shared__ int hist[2048];
  int x = blockIdx.x;
  int s = x & 7, q = x >> 3;
  int b = q & (NSB - 1), gh = q >> 3;
  int g = gh * 8 + s;
  int tid = threadIdx.x;
  for (int i = tid; i < 2048; i += 1024) hist[i] = 0;
  __syncthreads();
  int e0 = g * ECAP + b * (ECAP / NSB);
  int nodebase = g * np;
  for (int e = tid; e < ECAP / NSB; e += 1024) {
    atomicAdd(&hist[dst[e0 + e] - nodebase], 1);
  }
  __syncthreads();
  for (int i = tid; i < np; i += 1024) part[((size_t)(g * NSB + b)) * 2048 + i] = hist[i];
}

__global__ __launch_bounds__(1024) void csr_scan(const int* __restrict__ part, int np,
    int* __restrict__ offb, int* __restrict__ deg, int* __restrict__ curs) {
  __shared__ int psum[1024];
  int g = blockIdx.x, tid = threadIdx.x;
  int i0 = 2 * tid, i1 = 2 * tid + 1;
  int p0[NSB], p1[NSB];
  int c0 = 0, c1 = 0;
#pragma unroll
  for (int b = 0; b < NSB; ++b) {
    p0[b] = (i0 < np) ? part[((size_t)(g * NSB + b)) * 2048 + i0] : 0;
    p1[b] = (i1 < np) ? part[((size_t)(g * NSB + b)) * 2048 + i1] : 0;
    c0 += p0[b]; c1 += p1[b];
  }
  int pair = c0 + c1;
  psum[tid] = pair;
  for (int s = 1; s < 1024; s <<= 1) {
    __syncthreads();
    int t = (tid >= s) ? psum[tid - s] : 0;
    __syncthreads();
    psum[tid] += t;
  }
  int excl = psum[tid] - pair;
  int ebase = g * ECAP;
  int nodebase = g * np;
  if (i0 < np) {
    int off = ebase + excl;
    offb[nodebase + i0] = off;
    deg[nodebase + i0] = c0;
    int cur = off;
#pragma unroll
    for (int b = 0; b < NSB; ++b) { curs[((size_t)(g * NSB + b)) * 2048 + i0] = cur; cur += p0[b]; }
  }
  if (i1 < np) {
    int off = ebase + excl + c0;
    offb[nodebase + i1] = off;
    deg[nodebase + i1] = c1;
    int cur = off;
#pragma unroll
    for (int b = 0; b < NSB; ++b) { curs[((size_t)(g * NSB + b)) * 2048 + i1] = cur; cur += p1[b]; }
  }
}

__global__ __launch_bounds__(1024) void csr_place(const int* __restrict__ src,
    const int* __restrict__ dst, int np, const int* __restrict__ curs,
    int* __restrict__ esort) {
  __shared__ int cur[2048];
  int x = blockIdx.x;
  int s = x & 7, q = x >> 3;
  int b = q & (NSB - 1), gh = q >> 3;
  int g = gh * 8 + s;
  int tid = threadIdx.x;
  for (int i = tid; i < np; i += 1024) cur[i] = curs[((size_t)(g * NSB + b)) * 2048 + i];
  __syncthreads();
  int e0 = g * ECAP + b * (ECAP / NSB);
  int nodebase = g * np;
  for (int e = tid; e < ECAP / NSB; e += 1024) {
    int ge = e0 + e;
    int p = atomicAdd(&cur[dst[ge] - nodebase], 1);
    esort[p] = src[ge];
  }
}

// ---------------- aggregate (layer 0): mean over incoming edges --------------
__global__ __launch_bounds__(256) void aggregate_kernel(const _Float16* __restrict__ xh,
    const int* __restrict__ offb, const int* __restrict__ deg, const int* __restrict__ esrc,
    _Float16* __restrict__ meanh, int np, int C) {
  int bid = blockIdx.x;
  int s = bid & 7, q = bid >> 3;
  int gsub = q / C, chunk = q - gsub * C;
  int g = gsub * 8 + s;
  int wave = threadIdx.x >> 6, lane = threadIdx.x & 63;
  int sub = lane >> 4, l = lane & 15;
  int local = chunk * 16 + wave * 4 + sub;
  if (local >= np) return;
  int w = g * np + local;
  int b = offb[w], c = deg[w];
  int e = b + c;
  float acc[8] = {0.f, 0.f, 0.f, 0.f, 0.f, 0.f, 0.f, 0.f};
  int i = b;
  for (; i + 4 <= e; i += 4) {
    int s0 = esrc[i], s1 = esrc[i + 1], s2 = esrc[i + 2], s3 = esrc[i + 3];
    f16x8 v0 = *(const f16x8*)(xh + (size_t)s0 * 128 + l * 8);
    f16x8 v1 = *(const f16x8*)(xh + (size_t)s1 * 128 + l * 8);
    f16x8 v2 = *(const f16x8*)(xh + (size_t)s2 * 128 + l * 8);
    f16x8 v3 = *(const f16x8*)(xh + (size_t)s3 * 128 + l * 8);
    f16x8 t = (v0 + v1) + (v2 + v3);
#pragma unroll
    for (int j = 0; j < 8; ++j) acc[j] += (float)t[j];
  }
  for (; i < e; ++i) {
    int srcn = esrc[i];
    f16x8 v = *(const f16x8*)(xh + (size_t)srcn * 128 + l * 8);
#pragma unroll
    for (int j = 0; j < 8; ++j) acc[j] += (float)v[j];
  }
  float inv = 1.f / (float)(c > 0 ? c : 1);
  f16x8 o;
#pragma unroll
  for (int j = 0; j < 8; ++j) o[j] = (_Float16)(acc[j] * inv);
  *(f16x8*)(meanh + (size_t)w * 128 + l * 8) = o;
}

// ---------------- aggregate (layers 1/2): pre-mapped edge list, -1 = dropped --
__global__ __launch_bounds__(256) void aggregate_f(const _Float16* __restrict__ xh,
    const int* __restrict__ offb0, const int* __restrict__ deg0, const int* __restrict__ esortl,
    const int* __restrict__ orig, _Float16* __restrict__ meanh, int np, int C) {
  int bid = blockIdx.x;
  int s = bid & 7, q = bid >> 3;
  int gsub = q / C, chunk = q - gsub * C;
  int g = gsub * 8 + s;
  int wave = threadIdx.x >> 6, lane = threadIdx.x & 63;
  int sub = lane >> 4, l = lane & 15;
  int local = chunk * 16 + wave * 4 + sub;
  if (local >= np) return;
  int w = g * np + local;
  int o = orig[w];
  int b = offb0[o], c0 = deg0[o];
  int e = b + c0;
  float acc[8] = {0.f, 0.f, 0.f, 0.f, 0.f, 0.f, 0.f, 0.f};
  int cnt = 0;
  const f16x8 zero = {(_Float16)0.f, (_Float16)0.f, (_Float16)0.f, (_Float16)0.f,
                      (_Float16)0.f, (_Float16)0.f, (_Float16)0.f, (_Float16)0.f};
  int i = b;
  for (; i + 4 <= e; i += 4) {
    int n0 = esortl[i], n1 = esortl[i + 1], n2 = esortl[i + 2], n3 = esortl[i + 3];
    f16x8 v0 = zero, v1 = zero, v2 = zero, v3 = zero;
    if (n0 >= 0) v0 = *(const f16x8*)(xh + (size_t)n0 * 128 + l * 8);
    if (n1 >= 0) v1 = *(const f16x8*)(xh + (size_t)n1 * 128 + l * 8);
    if (n2 >= 0) v2 = *(const f16x8*)(xh + (size_t)n2 * 128 + l * 8);
    if (n3 >= 0) v3 = *(const f16x8*)(xh + (size_t)n3 * 128 + l * 8);
    cnt += (n0 >= 0) + (n1 >= 0) + (n2 >= 0) + (n3 >= 0);
    f16x8 t = (v0 + v1) + (v2 + v3);
#pragma unroll
    for (int j = 0; j < 8; ++j) acc[j] += (float)t[j];
  }
  for (; i < e; ++i) {
    int sn = esortl[i];
    if (sn < 0) continue;
    ++cnt;
    f16x8 v = *(const f16x8*)(xh + (size_t)sn * 128 + l * 8);
#pragma unroll
    for (int j = 0; j < 8; ++j) acc[j] += (float)v[j];
  }
  float inv = 1.f / (float)(cnt > 0 ? cnt : 1);
  f16x8 ov;
#pragma unroll
  for (int j = 0; j < 8; ++j) ov[j] = (_Float16)(acc[j] * inv);
  *(f16x8*)(meanh + (size_t)w * 128 + l * 8) = ov;
}

// ---------------- fused SAGE transform + score (LDS weight stage, 8 waves) ----
__global__ __launch_bounds__(512) void sage_gemm(const _Float16* __restrict__ XH,
    const _Float16* MEANIN, _Float16* OUT, const _Float16* __restrict__ WH,
    const float* __restrict__ bl, const float* __restrict__ pw, float* __restrict__ sc,
    int n) {
  __shared__ _Float16 WB[4096 * 8];  // 64KB, layout [ks][nf][lane][8]
  int tid = threadIdx.x;
  for (int qq = tid; qq < 4096; qq += 512)
    *(f16x8*)(WB + qq * 8) = *(const f16x8*)(WH + (size_t)qq * 8);
  __syncthreads();
  int wave = tid >> 6, lane = tid & 63;
  int wrow0 = blockIdx.x * RPB + wave * 64;
  if (wrow0 >= n) return;
  int kb = (lane >> 4) << 3;
  int lr = lane & 15;
  f32x4 acc[4][8];
#pragma unroll
  for (int t = 0; t < 4; ++t)
#pragma unroll
    for (int nf = 0; nf < 8; ++nf) acc[t][nf] = (f32x4){0.f, 0.f, 0.f, 0.f};
#pragma unroll
  for (int ks = 0; ks < 8; ++ks) {
    const _Float16* A = (ks < 4) ? MEANIN : XH;
    const _Float16* ap = A + (size_t)(wrow0 + lr) * 128 + (ks & 3) * 32 + kb;
    f16x8 a0 = *(const f16x8*)(ap);
    f16x8 a1 = *(const f16x8*)(ap + 16 * 128);
    f16x8 a2 = *(const f16x8*)(ap + 32 * 128);
    f16x8 a3 = *(const f16x8*)(ap + 48 * 128);
#pragma unroll
    for (int nf = 0; nf < 8; ++nf) {
      f16x8 b = *(const f16x8*)(WB + ((ks * 8 + nf) * 64 + lane) * 8);
      acc[0][nf] = __builtin_amdgcn_mfma_f32_16x16x32_f16(a0, b, acc[0][nf], 0, 0, 0);
      acc[1][nf] = __builtin_amdgcn_mfma_f32_16x16x32_f16(a1, b, acc[1][nf], 0, 0, 0);
      acc[2][nf] = __builtin_amdgcn_mfma_f32_16x16x32_f16(a2, b, acc[2][nf], 0, 0, 0);
      acc[3][nf] = __builtin_amdgcn_mfma_f32_16x16x32_f16(a3, b, acc[3][nf], 0, 0, 0);
    }
  }
  float pwv[8], qn = 0.f;
#pragma unroll
  for (int nf = 0; nf < 8; ++nf) {
    pwv[nf] = pw[nf * 16 + lr];
    qn += pwv[nf] * pwv[nf];
  }
#pragma unroll
  for (int o = 1; o < 16; o <<= 1) qn += __shfl_xor(qn, o);
  float inv_n = 1.f / sqrtf(qn);
#pragma unroll
  for (int t = 0; t < 4; ++t) {
    int rbase = wrow0 + t * 16 + ((lane >> 4) << 2);
    float dot[4] = {0.f, 0.f, 0.f, 0.f};
#pragma unroll
    for (int nf = 0; nf < 8; ++nf) {
      int col = nf * 16 + lr;
      float bias = bl[col];
#pragma unroll
      for (int r = 0; r < 4; ++r) {
        float v = fmaxf(acc[t][nf][r] + bias, 0.f);
        OUT[(size_t)(rbase + r) * 128 + col] = (_Float16)v;
        dot[r] += v * pwv[nf];
      }
    }
#pragma unroll
    for (int r = 0; r < 4; ++r) {
#pragma unroll
      for (int o = 1; o < 16; o <<= 1) dot[r] += __shfl_xor(dot[r], o);
    }
    if (lr == 0) {
#pragma unroll
      for (int r = 0; r < 4; ++r) sc[rbase + r] = tanhf(dot[r] * inv_n);
    }
  }
}

// ---------------- top-k sort: bitonic + NOO map + rank table + edge remap ----
// one block per graph. mode 0: write nooA + remap esort0->esortl via own map.
// mode 1: compose with nooA (layer-0 map) + remap esort0->esortl via composed.
// mode 2: rank table only.
__global__ __launch_bounds__(1024) void topk_sort(const float* __restrict__ sc,
    int n_per, int k, int* __restrict__ nooA, int* __restrict__ rankt,
    const int* __restrict__ esort0, int* __restrict__ esortl, int mode) {
  __shared__ unsigned long long L[2048];
  __shared__ int c2n[2048];
  int* comp = (int*)L;   // reused after sort for the orig->new map
  int g = blockIdx.x;
  int tid = threadIdx.x;
  int lane = tid & 63, wave = tid >> 6;
  int i0 = wave * 128 + lane;
  int i1 = i0 + 64;
  const float* scg = sc + g * n_per;
  auto keyize = [&](int i) -> unsigned long long {
    float f = (i < n_per) ? scg[i] : -FLT_MAX;
    unsigned u = __float_as_uint(f);
    u = (u & 0x80000000u) ? ~u : (u | 0x80000000u);  // monotone float->uint map
    return ((unsigned long long)u << 32) | (unsigned)(2047 - i);
  };
  unsigned long long a = keyize(i0), b = keyize(i1);
#pragma clang loop unroll(disable)
  for (unsigned kk = 2; kk <= 2048; kk <<= 1) {
#pragma clang loop unroll(disable)
    for (unsigned j = kk >> 1; j >= 128; j >>= 1) {
      L[i0] = a; L[i1] = b;
      __syncthreads();
      unsigned long long pa = L[i0 ^ j], pb = L[i1 ^ j];
      bool dA = ((i0 & kk) == 0), lA = ((i0 & j) == 0);
      if ((dA == lA) ? (pa > a) : (pa < a)) a = pa;
      bool dB = ((i1 & kk) == 0), lB = ((i1 & j) == 0);
      if ((dB == lB) ? (pb > b) : (pb < b)) b = pb;
      __syncthreads();
    }
    if (kk >= 128) {
      bool desc = ((i0 & kk) == 0);
      if ((a < b) == desc) { unsigned long long t = a; a = b; b = t; }
    }
    unsigned jtop = (kk >> 1 < 32u) ? (kk >> 1) : 32u;
#pragma clang loop unroll(disable)
    for (unsigned j = jtop; j >= 1; j >>= 1) {
      unsigned long long oa = __shfl_xor(a, (int)j);
      unsigned long long ob = __shfl_xor(b, (int)j);
      bool low = ((lane & j) == 0);
      bool dA = ((i0 & kk) == 0);
      if ((dA == low) ? (oa > a) : (oa < a)) a = oa;
      bool dB = ((i1 & kk) == 0);
      if ((dB == low) ? (ob > b) : (ob < b)) b = ob;
    }
  }
  int orig_a = 2047 - (int)(a & 0xFFFFFFFFu);
  int orig_b = 2047 - (int)(b & 0xFFFFFFFFu);
  if (i0 < k) rankt[g * NPG + i0] = orig_a;
  if (i1 < k) rankt[g * NPG + i1] = orig_b;
  if (mode == 0) {
    // full map for this graph (n_per == NPG, every orig covered)
    int na = (i0 < k) ? g * k + i0 : -1;
    int nb = (i1 < k) ? g * k + i1 : -1;
    nooA[g * n_per + orig_a] = na;
    nooA[g * n_per + orig_b] = nb;
    c2n[orig_a] = na;
    c2n[orig_b] = nb;
    __syncthreads();
    for (int e = tid; e < ECAP; e += 1024) {
      int v = esort0[g * ECAP + e];
      esortl[g * ECAP + e] = c2n[v - g * NPG];
    }
  } else if (mode == 1) {
    if (orig_a < n_per) c2n[orig_a] = (i0 < k) ? g * k + i0 : -1;
    if (orig_b < n_per) c2n[orig_b] = (i1 < k) ? g * k + i1 : -1;
    __syncthreads();
    for (int o2 = tid; o2 < NPG; o2 += 1024) {
      int a0 = nooA[g * NPG + o2];
      comp[o2] = (a0 >= 0) ? c2n[a0 - g * n_per] : -1;
    }
    __syncthreads();
    for (int e = tid; e < ECAP; e += 1024) {
      int v = esort0[g * ECAP + e];
      esortl[g * ECAP + e] = comp[v - g * NPG];
    }
  }
}

// ---------------- top-k tail: gather+scale+XH write+ORIG+readout partials -----
__global__ __launch_bounds__(256) void topk_tail(const float* __restrict__ sc,
    const int* __restrict__ rankt, int n_per, int k, const _Float16* __restrict__ meanin,
    _Float16* __restrict__ xh, const int* __restrict__ orig_in, int* __restrict__ orig_out,
    float* __restrict__ pmax, float* __restrict__ psum) {
  int g = blockIdx.x >> 4;
  int slice = blockIdx.x & (RSL - 1);
  int rpb = (k + RSL - 1) / RSL;
  int r0 = slice * rpb;
  int r1 = r0 + rpb; if (r1 > k) r1 = k;
  const float* scg = sc + g * n_per;
  int grp = threadIdx.x >> 4, l8 = threadIdx.x & 15;
  float vmax[8], vsum[8];
#pragma unroll
  for (int j = 0; j < 8; ++j) { vmax[j] = -FLT_MAX; vsum[j] = 0.f; }
  for (int r = r0 + grp; r < r1; r += 16) {
    int orig = rankt[g * NPG + r];
    int p = g * n_per + orig;
    float score = scg[orig];
    f16x8 v = *(const f16x8*)(meanin + (size_t)p * 128 + l8 * 8);
    f16x8 ovv;
#pragma unroll
    for (int j = 0; j < 8; ++j) {
      float val = (float)v[j] * score;
      ovv[j] = (_Float16)val;
      vmax[j] = fmaxf(vmax[j], val);
      vsum[j] += val;
    }
    *(f16x8*)(xh + (size_t)(g * k + r) * 128 + l8 * 8) = ovv;
    if (l8 == 0) orig_out[g * k + r] = orig_in ? orig_in[p] : p;
  }
  __shared__ float smax[4 * 128], ssum[4 * 128];
  int lane = threadIdx.x & 63, wave = threadIdx.x >> 6;
#pragma unroll
  for (int j = 0; j < 8; ++j) {
    vmax[j] = fmaxf(vmax[j], __shfl_xor(vmax[j], 16));
    vmax[j] = fmaxf(vmax[j], __shfl_xor(vmax[j], 32));
    vsum[j] += __shfl_xor(vsum[j], 16);
    vsum[j] += __shfl_xor(vsum[j], 32);
  }
  if ((lane >> 4) == 0) {
#pragma unroll
    for (int j = 0; j < 8; ++j) {
      smax[wave * 128 + l8 * 8 + j] = vmax[j];
      ssum[wave * 128 + l8 * 8 + j] = vsum[j];
    }
  }
  __syncthreads();
  if (threadIdx.x < 128) {
    int d = threadIdx.x;
    float m = fmaxf(fmaxf(smax[d], smax[128 + d]), fmaxf(smax[256 + d], smax[384 + d]));
    float s2 = ssum[d] + ssum[128 + d] + ssum[256 + d] + ssum[384 + d];
    pmax[(size_t)(g * RSL + slice) * 128 + d] = m;
    psum[(size_t)(g * RSL + slice) * 128 + d] = s2;
  }
}

// ---------------- fused readout-combine (3 layers) + MLP ----------------------
__global__ __launch_bounds__(256) void mlp_fused(const float* __restrict__ pmax,
    const float* __restrict__ psum, int k0, int k1, int k2,
    const float* __restrict__ W1, const float* __restrict__ b1,
    const float* __restrict__ W2, const float* __restrict__ b2,
    const float* __restrict__ W3, const float* __restrict__ b3, float* __restrict__ out) {
  __shared__ float h[256], h1[128], h2[64];
  int g = blockIdx.x, t = threadIdx.x;
  int ks[3] = {k0, k1, k2};
  if (t < 128) {
    float hm = 0.f, hs = 0.f;
#pragma unroll
    for (int li = 0; li < 3; ++li) {
      const float* pm = pmax + ((size_t)li * GRAPHS + g) * RSL * 128;
      const float* ps = psum + ((size_t)li * GRAPHS + g) * RSL * 128;
      float m = -FLT_MAX, s = 0.f;
#pragma unroll
      for (int sl = 0; sl < RSL; ++sl) {
        m = fmaxf(m, pm[sl * 128 + t]);
        s += ps[sl * 128 + t];
      }
      hm += m;
      hs += s / (float)ks[li];
    }
    h[t] = hm;
    h[128 + t] = hs;
  }
  __syncthreads();
  if (t < 128) {
    const float* wp = W1 + t * 256;
    float a = b1[t];
    for (int c = 0; c < 256; ++c) a += h[c] * wp[c];
    h1[t] = fmaxf(a, 0.f);
  }
  __syncthreads();
  if (t < 64) {
    const float* wp = W2 + t * 128;
    float a = b2[t];
    for (int c = 0; c < 128; ++c) a += h1[c] * wp[c];
    h2[t] = fmaxf(a, 0.f);
  }
  __syncthreads();
  if (t < 64) {
    float a = h2[t] * W3[t];
#pragma unroll
    for (int o = 32; o >= 1; o >>= 1) a += __shfl_xor(a, o);
    if (t == 0) out[g] = 1.f / (1.f + expf(-(a + b3[0])));
  }
}

extern "C" void kernel_launch(void* const* d_in, const int* in_sizes, int n_in,
                              void* d_out, int out_size, void* d_ws, size_t ws_size,
                              hipStream_t stream) {
  const int* node_ids = (const int*)d_in[0];
  const int* ei = (const int*)d_in[1];
  const float* emb = (const float*)d_in[3];
  const float* W[3][4] = {
      {(const float*)d_in[4], (const float*)d_in[5], (const float*)d_in[6], (const float*)d_in[7]},
      {(const float*)d_in[8], (const float*)d_in[9], (const float*)d_in[10], (const float*)d_in[11]},
      {(const float*)d_in[12], (const float*)d_in[13], (const float*)d_in[14], (const float*)d_in[15]}};
  const float* W1 = (const float*)d_in[16];
  const float* b1 = (const float*)d_in[17];
  const float* W2 = (const float*)d_in[18];
  const float* b2 = (const float*)d_in[19];
  const float* W3 = (const float*)d_in[20];
  const float* b3 = (const float*)d_in[21];
  float* out = (float*)d_out;

  const int E = NEDGES;
  char* ws = (char*)d_ws;
  size_t o = 0;
  auto alloc = [&](size_t bytes) { void* p = ws + o; o = (o + bytes + 255) & ~(size_t)255; return p; };
  _Float16* XH = (_Float16*)alloc((size_t)NNODES * 128 * 2);
  _Float16* MEANH = (_Float16*)alloc((size_t)NNODES * 128 * 2);
  int* ESORT = (int*)alloc((size_t)E * 4);
  int* ESORTL = (int*)alloc((size_t)E * 4);
  int* PART = (int*)alloc((size_t)GRAPHS * NSB * 2048 * 4);
  int* CURS = (int*)alloc((size_t)GRAPHS * NSB * 2048 * 4);
  int* OFFB = (int*)alloc((size_t)NNODES * 4);
  int* DEG = (int*)alloc((size_t)NNODES * 4);
  float* SC = (float*)alloc((size_t)NNODES * 4);
  int* NOOA = (int*)alloc((size_t)NNODES * 4);
  int* RANKT = (int*)alloc((size_t)NNODES * 4);
  int* ORIGA = (int*)alloc((size_t)NNODES * 4);
  int* ORIGB = (int*)alloc((size_t)NNODES * 4);
  _Float16* WH0 = (_Float16*)alloc(4096 * 8 * 2);
  _Float16* WH1 = (_Float16*)alloc(4096 * 8 * 2);
  _Float16* WH2 = (_Float16*)alloc(4096 * 8 * 2);
  float* PMAX = (float*)alloc((size_t)3 * GRAPHS * RSL * 128 * 4);
  float* PSUM = (float*)alloc((size_t)3 * GRAPHS * RSL * 128 * 4);

  embed_kernel<<<NNODES * 16 / 256, 256, 0, stream>>>(node_ids, emb, XH);
  convert_w3<<<48, 256, 0, stream>>>(W[0][0], W[0][1], W[1][0], W[1][1], W[2][0], W[2][1],
                                     WH0, WH1, WH2);

  // layer-0 CSR (built once; topk_sort remaps values for layers 1/2)
  const int* src = ei;
  const int* dst = ei + E;
  csr_hist<<<GRAPHS * NSB, 1024, 0, stream>>>(src, dst, NPG, PART);
  csr_scan<<<GRAPHS, 1024, 0, stream>>>(PART, NPG, OFFB, DEG, CURS);
  csr_place<<<GRAPHS * NSB, 1024, 0, stream>>>(src, dst, NPG, CURS, ESORT);

  struct LayerP { int n, k; };                 // n = current node count; k = keep per graph
  LayerP L[3] = {{131072, 1639}, {104896, 1312}, {83968, 1050}};
  _Float16* WHs[3] = {WH0, WH1, WH2};
  int* ORIG_cur = ORIGA;   // maps current ids -> original ids (valid for li>=1)
  int* ORIG_next = ORIGB;

  for (int li = 0; li < 3; ++li) {
    int n = L[li].n, k = L[li].k;
    int np = n / 64;
    const float *bl = W[li][2], *pw = W[li][3];

    int C = (np + 15) / 16;
    if (li == 0) {
      aggregate_kernel<<<64 * C, 256, 0, stream>>>(XH, OFFB, DEG, ESORT, MEANH, np, C);
    } else {
      aggregate_f<<<64 * C, 256, 0, stream>>>(XH, OFFB, DEG, ESORTL, ORIG_cur,
                                              MEANH, np, C);
    }
    sage_gemm<<<(n + RPB - 1) / RPB, 512, 0, stream>>>(XH, MEANH, MEANH, WHs[li], bl, pw, SC, n);
    topk_sort<<<GRAPHS, 1024, 0, stream>>>(SC, np, k, NOOA, RANKT, ESORT, ESORTL, li);
    topk_tail<<<GRAPHS * RSL, 256, 0, stream>>>(SC, RANKT, np, k, MEANH, XH,
        (li == 0) ? nullptr : ORIG_cur, ORIG_next,
        PMAX + (size_t)li * GRAPHS * RSL * 128, PSUM + (size_t)li * GRAPHS * RSL * 128);
    { int* t = ORIG_cur; ORIG_cur = ORIG_next; ORIG_next = t; }
  }

  mlp_fused<<<GRAPHS, 256, 0, stream>>>(PMAX, PSUM, L[0].k, L[1].k, L[2].k,
                                        W1, b1, W2, b2, W3, b3, out);
}